// Round 4
// baseline (631.817 us; speedup 1.0000x reference)
//
#include <hip/hip_runtime.h>
#include <hip/hip_bf16.h>
#include <stdint.h>
#include <stddef.h>

typedef __bf16 bf16;
typedef __attribute__((ext_vector_type(8))) __bf16 bf16x8;
typedef __attribute__((ext_vector_type(4))) __bf16 bf16x4;
typedef __attribute__((ext_vector_type(4))) float f32x4;

#define DM 2048      // model dim
#define NH 16        // heads
#define HDD 128      // head dim
#define BB 2         // batch
#define TT 2048      // seq len
#define MM (BB*TT)   // 4096 rows
#define NQKV (3*DM)  // 6144

#define L2E 1.4426950408889634f
#define ATT_SCALE 0.08838834764831845f   // 1/sqrt(128)
#define NEG_INF (-__builtin_inff())

static_assert(sizeof(bf16x8) == 16, "bf16x8 must be 16B");

// ---------------------------------------------------------------- helpers
static __device__ __forceinline__ void gload_lds16(const void* g, void* l) {
  __builtin_amdgcn_global_load_lds(
      (__attribute__((address_space(1))) void*)g,
      (__attribute__((address_space(3))) void*)l, 16, 0, 0);
}

// ---------------------------------------------------------------- pre-pass
__global__ __launch_bounds__(256) void rope_table_k(float* __restrict__ cT,
                                                    float* __restrict__ sT) {
  int id = blockIdx.x * 256 + threadIdx.x;          // < 2048*64
  int t = id >> 6, i = id & 63;
  float freq = powf(10000.0f, -(float)i * (1.0f / 64.0f));
  float theta = (float)t * freq;
  float s, c;
  __sincosf(theta, &s, &c);
  cT[id] = c;
  sT[id] = s;
}

__global__ __launch_bounds__(256) void convert_x_k(const float* __restrict__ x,
                                                   bf16* __restrict__ xb) {
  size_t id = (size_t)blockIdx.x * 256 + threadIdx.x;
  size_t o = id * 8;
  float4 a = *(const float4*)(x + o);
  float4 b = *(const float4*)(x + o + 4);
  bf16x8 r;
  r[0] = (bf16)a.x; r[1] = (bf16)a.y; r[2] = (bf16)a.z; r[3] = (bf16)a.w;
  r[4] = (bf16)b.x; r[5] = (bf16)b.y; r[6] = (bf16)b.z; r[7] = (bf16)b.w;
  *(bf16x8*)(xb + o) = r;
}

// W (K x N) f32 -> Wt (N x K) bf16, 64x64 tiles
__global__ __launch_bounds__(256) void transpose_w_k(const float* __restrict__ W,
                                                     bf16* __restrict__ Wt,
                                                     int K, int N) {
  __shared__ float tile[64][65];
  int n0 = blockIdx.x * 64, k0 = blockIdx.y * 64;
  int t = threadIdx.x;
#pragma unroll
  for (int i = 0; i < 16; ++i) {
    int idx = t + i * 256;
    int r = idx >> 6, c = idx & 63;
    tile[r][c] = W[(size_t)(k0 + r) * N + n0 + c];
  }
  __syncthreads();
#pragma unroll
  for (int i = 0; i < 16; ++i) {
    int idx = t + i * 256;
    int r = idx >> 6, c = idx & 63;
    Wt[(size_t)(n0 + r) * K + k0 + c] = (bf16)tile[c][r];
  }
}

// in-place RoPE on (b,h,t,hd) bf16 buffer; half-split style
__global__ __launch_bounds__(256) void rope_apply_k(bf16* __restrict__ buf,
                                                    const float* __restrict__ cT,
                                                    const float* __restrict__ sT) {
  int id = blockIdx.x * 256 + threadIdx.x;   // < 32*2048*16
  int i4 = id & 15;
  int t = (id >> 4) & 2047;
  int bh = id >> 15;
  int idx0 = i4 * 4;
  size_t base = ((size_t)bh * TT + t) * HDD;
  bf16x4 x1 = *(const bf16x4*)(buf + base + idx0);
  bf16x4 x2 = *(const bf16x4*)(buf + base + 64 + idx0);
  float4 ct = *(const float4*)(cT + t * 64 + idx0);
  float4 st = *(const float4*)(sT + t * 64 + idx0);
  bf16x4 o1, o2;
  float c0, s0, a, b2;
#pragma unroll
  for (int j = 0; j < 4; ++j) {
    c0 = (j == 0) ? ct.x : (j == 1) ? ct.y : (j == 2) ? ct.z : ct.w;
    s0 = (j == 0) ? st.x : (j == 1) ? st.y : (j == 2) ? st.z : st.w;
    a = (float)x1[j];
    b2 = (float)x2[j];
    o1[j] = (bf16)(a * c0 - b2 * s0);
    o2[j] = (bf16)(a * s0 + b2 * c0);
  }
  *(bf16x4*)(buf + base + idx0) = o1;
  *(bf16x4*)(buf + base + 64 + idx0) = o2;
}

// ---------------------------------------------------------------- GEMM
// C(M,N) = A(M,K) * Bt(N,K)^T + bias.  128x128 tile, BK=64, 4 waves 2x2.
// XCD-aware bijective swizzle (nwg % 8 == 0 for both call sites).
template <int EPI>
__global__ __launch_bounds__(256, 2) void gemm_bt_k(
    const bf16* __restrict__ A, const bf16* __restrict__ Bt,
    const float* __restrict__ bias,
    bf16* __restrict__ q_out, bf16* __restrict__ k_out, bf16* __restrict__ v_out,
    float* __restrict__ c_out, int M, int N, int K) {
  __shared__ __align__(16) bf16 Asm[128 * 64];
  __shared__ __align__(16) bf16 Bsm[128 * 64];
  const int tid = threadIdx.x;
  const int w = tid >> 6, l = tid & 63;
  const int lane16 = l & 15, lgrp = l >> 4;
  const int wm = w >> 1, wn = w & 1;

  int flat = blockIdx.y * gridDim.x + blockIdx.x;
  {
    const int nwg = gridDim.x * gridDim.y;
    const int cpx = nwg >> 3;
    flat = (flat & 7) * cpx + (flat >> 3);
  }
  const int bm = flat % gridDim.x;
  const int bn = flat / gridDim.x;

  const int l8r = l >> 3, l8c = l & 7;

  f32x4 acc[4][4] = {};

  for (int k0 = 0; k0 < K; k0 += 64) {
    __syncthreads();
#pragma unroll
    for (int i = 0; i < 4; ++i) {
      int slot = w * 4 + i;
      int row = slot * 8 + l8r;
      gload_lds16(A + (size_t)(bm * 128 + row) * K + k0 + l8c * 8,
                  &Asm[slot * 512]);
      gload_lds16(Bt + (size_t)(bn * 128 + row) * K + k0 + l8c * 8,
                  &Bsm[slot * 512]);
    }
    __syncthreads();
#pragma unroll
    for (int kk = 0; kk < 2; ++kk) {
      bf16x8 af[4], bfr[4];
#pragma unroll
      for (int mf = 0; mf < 4; ++mf) {
        int row = wm * 64 + mf * 16 + lane16;
        af[mf] = *(const bf16x8*)&Asm[row * 64 + kk * 32 + lgrp * 8];
      }
#pragma unroll
      for (int nf = 0; nf < 4; ++nf) {
        int col = wn * 64 + nf * 16 + lane16;
        bfr[nf] = *(const bf16x8*)&Bsm[col * 64 + kk * 32 + lgrp * 8];
      }
#pragma unroll
      for (int mf = 0; mf < 4; ++mf)
#pragma unroll
        for (int nf = 0; nf < 4; ++nf)
          acc[mf][nf] = __builtin_amdgcn_mfma_f32_16x16x32_bf16(
              af[mf], bfr[nf], acc[mf][nf], 0, 0, 0);
    }
  }

  if (EPI == 0) {
    const int which = bn >> 4;
    const int head = bn & 15;
    bf16* outb = (which == 0) ? q_out : (which == 1 ? k_out : v_out);
#pragma unroll
    for (int nf = 0; nf < 4; ++nf) {
      int hd = wn * 64 + nf * 16 + lane16;
      float bv = bias[bn * 128 + hd];
#pragma unroll
      for (int mf = 0; mf < 4; ++mf)
#pragma unroll
        for (int r = 0; r < 4; ++r) {
          int row = bm * 128 + wm * 64 + mf * 16 + lgrp * 4 + r;
          int b = row >> 11, t = row & 2047;
          outb[((size_t)(b * NH + head) * TT + t) * HDD + hd] =
              (bf16)(acc[mf][nf][r] + bv);
        }
    }
  } else {
#pragma unroll
    for (int nf = 0; nf < 4; ++nf) {
      int colg = bn * 128 + wn * 64 + nf * 16 + lane16;
      float bv = bias[colg];
#pragma unroll
      for (int mf = 0; mf < 4; ++mf)
#pragma unroll
        for (int r = 0; r < 4; ++r) {
          int row = bm * 128 + wm * 64 + mf * 16 + lgrp * 4 + r;
          c_out[(size_t)row * N + colg] = acc[mf][nf][r] + bv;
        }
    }
  }
}

// ---------------------------------------------------------------- attention
// grid (16, B*H) = 512 blocks, 4 waves; block does q-tiles {bx, 31-bx}
// (64 rows each) -> exactly 33 K-tiles per block, 2 blocks/CU resident.
// Wave w owns q-rows [q0 + 16w, q0 + 16w + 16).
// Tile pipeline is the R2-proven structure: reg-stage K+V -> __syncthreads ->
// LDS write -> __syncthreads -> compute. No raw barriers.
__global__ __launch_bounds__(256, 4) void attn_k(
    const bf16* __restrict__ Q, const bf16* __restrict__ Kt,
    const bf16* __restrict__ V, bf16* __restrict__ Y) {
  __shared__ __align__(16) bf16 Ksm[64 * 128];   // [key][hd], row-swizzled, 16KB
  __shared__ __align__(16) bf16 Vsm[128 * 64];   // [hd][key], row-swizzled, 16KB
  __shared__ __align__(16) bf16 Psm[4][16 * 64]; // per-wave P, swizzled, 8KB
  const int tid = threadIdx.x, w = tid >> 6, l = tid & 63;
  const int lane16 = l & 15, lgrp = l >> 4;
  const int bh = blockIdx.y;
  const int b = bh >> 4, h = bh & 15;
  const size_t base = (size_t)bh * TT * HDD;

  uint4 kreg[4], vreg[4];
  const int vg = tid >> 4, vh8 = tid & 15;

  auto load_tile = [&](int k0) {
#pragma unroll
    for (int i = 0; i < 4; ++i) {
      int flat8 = tid * 4 + i;
      int key = flat8 >> 4, hb = flat8 & 15;
      kreg[i] = *(const uint4*)(Kt + base + (size_t)(k0 + key) * HDD + hb * 8);
    }
#pragma unroll
    for (int kq = 0; kq < 4; ++kq)
      vreg[kq] = *(const uint4*)(V + base + (size_t)(k0 + vg * 4 + kq) * HDD + vh8 * 8);
  };
  auto write_tile = [&]() {
#pragma unroll
    for (int i = 0; i < 4; ++i) {
      int flat8 = tid * 4 + i;
      int key = flat8 >> 4, hb = flat8 & 15;
      int byte = (hb * 16) ^ ((key & 7) << 4);
      *(uint4*)((char*)Ksm + key * 256 + byte) = kreg[i];
    }
    const unsigned* dw = (const unsigned*)vreg;
    int hd0 = vh8 * 8;
#pragma unroll
    for (int j = 0; j < 8; ++j) {
      int ww = j >> 1;
      unsigned sel = (j & 1) ? 0x07060302u : 0x05040100u;
      uint2 val;
      val.x = __builtin_amdgcn_perm(dw[4 + ww], dw[0 + ww], sel);   // keys 0,1
      val.y = __builtin_amdgcn_perm(dw[12 + ww], dw[8 + ww], sel);  // keys 2,3
      int hd = hd0 + j;
      int swz = ((hd & 7) ^ ((hd >> 3) & 7)) << 4;
      *(uint2*)((char*)Vsm + hd * 128 + ((vg * 8) ^ swz)) = val;
    }
  };

  for (int pass = 0; pass < 2; ++pass) {
    const int qt = (pass == 0) ? (int)blockIdx.x : 31 - (int)blockIdx.x;
    const int q0 = qt * 64;
    const int nt = qt + 1;

    // Q fragments (registers)
    bf16x8 qa[4];
    {
      int row = q0 + w * 16 + lane16;
#pragma unroll
      for (int kk = 0; kk < 4; ++kk)
        qa[kk] = *(const bf16x8*)(Q + base + (size_t)row * HDD + kk * 32 + lgrp * 8);
    }

    f32x4 o[8] = {};
    float m_r[4], l_r[4];
#pragma unroll
    for (int r = 0; r < 4; ++r) { m_r[r] = NEG_INF; l_r[r] = 0.f; }

    for (int kt = 0; kt < nt; ++kt) {
      const int k0 = kt * 64;
      load_tile(k0);
      __syncthreads();          // all waves done reading LDS (prev tile / prev pass)
      write_tile();
      __syncthreads();          // K/V staged

      // ---- S = Q K^T
      f32x4 s[4] = {};
#pragma unroll
      for (int kk = 0; kk < 4; ++kk) {
        bf16x8 kf[4];
#pragma unroll
        for (int nf = 0; nf < 4; ++nf) {
          int key = nf * 16 + lane16;
          int byte = ((kk * 32 + lgrp * 8) * 2) ^ ((key & 7) << 4);
          kf[nf] = *(const bf16x8*)((char*)Ksm + key * 256 + byte);
        }
#pragma unroll
        for (int nf = 0; nf < 4; ++nf)
          s[nf] = __builtin_amdgcn_mfma_f32_16x16x32_bf16(
              qa[kk], kf[nf], s[nf], 0, 0, 0);
      }

      // ---- scale + causal mask
      const int rowbase = q0 + w * 16 + lgrp * 4;
      const bool needmask = (k0 + 63 > q0 + w * 16);
#pragma unroll
      for (int nf = 0; nf < 4; ++nf) {
        int col = k0 + nf * 16 + lane16;
#pragma unroll
        for (int r = 0; r < 4; ++r) {
          float sv = s[nf][r] * ATT_SCALE;
          if (needmask && col > rowbase + r) sv = -3.0e38f;
          s[nf][r] = sv;
        }
      }

      // ---- online softmax (R2-proven math)
#pragma unroll
      for (int r = 0; r < 4; ++r) {
        float tm = fmaxf(fmaxf(s[0][r], s[1][r]), fmaxf(s[2][r], s[3][r]));
        tm = fmaxf(tm, __shfl_xor(tm, 1));
        tm = fmaxf(tm, __shfl_xor(tm, 2));
        tm = fmaxf(tm, __shfl_xor(tm, 4));
        tm = fmaxf(tm, __shfl_xor(tm, 8));
        float mo = m_r[r];
        float mn, alpha;
        if (tm > -1e37f) {
          mn = fmaxf(mo, tm);
          alpha = exp2f((mo - mn) * L2E);
        } else {
          mn = mo;
          alpha = 1.0f;
        }
        m_r[r] = mn;
        float rs = 0.f;
#pragma unroll
        for (int nf = 0; nf < 4; ++nf) {
          float p = exp2f((s[nf][r] - mn) * L2E);
          s[nf][r] = p;
          rs += p;
        }
        rs += __shfl_xor(rs, 1);
        rs += __shfl_xor(rs, 2);
        rs += __shfl_xor(rs, 4);
        rs += __shfl_xor(rs, 8);
        l_r[r] = l_r[r] * alpha + rs;
#pragma unroll
        for (int nf = 0; nf < 8; ++nf) o[nf][r] *= alpha;
      }

      // ---- P -> LDS (per-wave region, same-wave readback)
#pragma unroll
      for (int nf = 0; nf < 4; ++nf)
#pragma unroll
        for (int r = 0; r < 4; ++r) {
          int rl = lgrp * 4 + r;
          int byte = ((nf * 16 + lane16) * 2) ^ ((rl & 7) << 4);
          *(bf16*)((char*)&Psm[w][0] + rl * 128 + byte) = (bf16)s[nf][r];
        }
      bf16x8 pa[2];
#pragma unroll
      for (int kf2 = 0; kf2 < 2; ++kf2) {
        int byte = ((kf2 * 32 + lgrp * 8) * 2) ^ ((lane16 & 7) << 4);
        pa[kf2] = *(const bf16x8*)((char*)&Psm[w][0] + lane16 * 128 + byte);
      }

      // ---- O += P V
#pragma unroll
      for (int nf = 0; nf < 8; ++nf) {
#pragma unroll
        for (int kf2 = 0; kf2 < 2; ++kf2) {
          int hd = nf * 16 + lane16;
          int byte = ((kf2 * 32 + lgrp * 8) * 2) ^ (((hd & 7) ^ ((hd >> 3) & 7)) << 4);
          bf16x8 vf = *(const bf16x8*)((char*)Vsm + hd * 128 + byte);
          o[nf] = __builtin_amdgcn_mfma_f32_16x16x32_bf16(
              pa[kf2], vf, o[nf], 0, 0, 0);
        }
      }
    }

    // ---- finalize: O / l -> Y (b,t,D) bf16
#pragma unroll
    for (int r = 0; r < 4; ++r) {
      float inv = 1.0f / l_r[r];
      int row = q0 + w * 16 + lgrp * 4 + r;
#pragma unroll
      for (int nf = 0; nf < 8; ++nf) {
        int hd = nf * 16 + lane16;
        Y[(size_t)(b * TT + row) * DM + h * HDD + hd] = (bf16)(o[nf][r] * inv);
      }
    }
  }
}

// ---------------------------------------------------------------- launch
extern "C" void kernel_launch(void* const* d_in, const int* in_sizes, int n_in,
                              void* d_out, int out_size, void* d_ws, size_t ws_size,
                              hipStream_t stream) {
  const float* x = (const float*)d_in[0];
  const float* Wqkv = (const float*)d_in[2];
  const float* bqkv = (const float*)d_in[3];
  const float* Wproj = (const float*)d_in[4];
  const float* bproj = (const float*)d_in[5];
  float* out = (float*)d_out;

  char* ws = (char*)d_ws;
  bf16* xb = (bf16*)ws;                 ws += (size_t)MM * DM * 2;
  bf16* Wqkvt = (bf16*)ws;              ws += (size_t)NQKV * DM * 2;
  bf16* Wprojt = (bf16*)ws;             ws += (size_t)DM * DM * 2;
  bf16* kb = (bf16*)ws;                 ws += (size_t)MM * DM * 2;
  bf16* vb = (bf16*)ws;                 ws += (size_t)MM * DM * 2;
  float* cosT = (float*)ws;             ws += (size_t)TT * 64 * 4;
  float* sinT = (float*)ws;             ws += (size_t)TT * 64 * 4;
  bf16* qb = (bf16*)d_out;              // q lives in d_out (overwritten by proj)
  bf16* yb = xb;                        // xb dead after QKV GEMM

  rope_table_k<<<dim3(512), dim3(256), 0, stream>>>(cosT, sinT);
  convert_x_k<<<dim3(4096), dim3(256), 0, stream>>>(x, xb);
  transpose_w_k<<<dim3(96, 32), dim3(256), 0, stream>>>(Wqkv, Wqkvt, DM, NQKV);
  transpose_w_k<<<dim3(32, 32), dim3(256), 0, stream>>>(Wproj, Wprojt, DM, DM);

  gemm_bt_k<0><<<dim3(32, 48), dim3(256), 0, stream>>>(
      xb, Wqkvt, bqkv, qb, kb, vb, nullptr, MM, NQKV, DM);

  rope_apply_k<<<dim3(4096), dim3(256), 0, stream>>>(qb, cosT, sinT);
  rope_apply_k<<<dim3(4096), dim3(256), 0, stream>>>(kb, cosT, sinT);

  attn_k<<<dim3(16, 32), dim3(256), 0, stream>>>(qb, kb, vb, yb);

  gemm_bt_k<1><<<dim3(32, 16), dim3(256), 0, stream>>>(
      yb, Wprojt, bproj, nullptr, nullptr, nullptr, out, MM, DM, DM);
}

// Round 5
// 332.768 us; speedup vs baseline: 1.8987x; 1.8987x over previous
//
#include <hip/hip_runtime.h>
#include <hip/hip_bf16.h>
#include <stdint.h>
#include <stddef.h>

typedef __bf16 bf16;
typedef __attribute__((ext_vector_type(8))) __bf16 bf16x8;
typedef __attribute__((ext_vector_type(4))) __bf16 bf16x4;
typedef __attribute__((ext_vector_type(4))) float f32x4;

#define DM 2048      // model dim
#define NH 16        // heads
#define HDD 128      // head dim
#define BB 2         // batch
#define TT 2048      // seq len
#define MM (BB*TT)   // 4096 rows
#define NQKV (3*DM)  // 6144

#define L2E 1.4426950408889634f
#define ATT_SCALE 0.08838834764831845f   // 1/sqrt(128)
#define NEG_INF (-__builtin_inff())

static_assert(sizeof(bf16x8) == 16, "bf16x8 must be 16B");

// ---------------------------------------------------------------- helpers
static __device__ __forceinline__ void gload_lds16(const void* g, void* l) {
  __builtin_amdgcn_global_load_lds(
      (__attribute__((address_space(1))) void*)g,
      (__attribute__((address_space(3))) void*)l, 16, 0, 0);
}

// ---------------------------------------------------------------- pre-pass
__global__ __launch_bounds__(256) void rope_table_k(float* __restrict__ cT,
                                                    float* __restrict__ sT) {
  int id = blockIdx.x * 256 + threadIdx.x;          // < 2048*64
  int t = id >> 6, i = id & 63;
  float freq = powf(10000.0f, -(float)i * (1.0f / 64.0f));
  float theta = (float)t * freq;
  float s, c;
  __sincosf(theta, &s, &c);
  cT[id] = c;
  sT[id] = s;
}

__global__ __launch_bounds__(256) void convert_x_k(const float* __restrict__ x,
                                                   bf16* __restrict__ xb) {
  size_t id = (size_t)blockIdx.x * 256 + threadIdx.x;
  size_t o = id * 8;
  float4 a = *(const float4*)(x + o);
  float4 b = *(const float4*)(x + o + 4);
  bf16x8 r;
  r[0] = (bf16)a.x; r[1] = (bf16)a.y; r[2] = (bf16)a.z; r[3] = (bf16)a.w;
  r[4] = (bf16)b.x; r[5] = (bf16)b.y; r[6] = (bf16)b.z; r[7] = (bf16)b.w;
  *(bf16x8*)(xb + o) = r;
}

// W (K x N) f32 -> Wt (N x K) bf16, 64x64 tiles
__global__ __launch_bounds__(256) void transpose_w_k(const float* __restrict__ W,
                                                     bf16* __restrict__ Wt,
                                                     int K, int N) {
  __shared__ float tile[64][65];
  int n0 = blockIdx.x * 64, k0 = blockIdx.y * 64;
  int t = threadIdx.x;
#pragma unroll
  for (int i = 0; i < 16; ++i) {
    int idx = t + i * 256;
    int r = idx >> 6, c = idx & 63;
    tile[r][c] = W[(size_t)(k0 + r) * N + n0 + c];
  }
  __syncthreads();
#pragma unroll
  for (int i = 0; i < 16; ++i) {
    int idx = t + i * 256;
    int r = idx >> 6, c = idx & 63;
    Wt[(size_t)(n0 + r) * K + k0 + c] = (bf16)tile[c][r];
  }
}

// in-place RoPE on (b,h,t,hd) bf16 buffer; half-split style
__global__ __launch_bounds__(256) void rope_apply_k(bf16* __restrict__ buf,
                                                    const float* __restrict__ cT,
                                                    const float* __restrict__ sT) {
  int id = blockIdx.x * 256 + threadIdx.x;   // < 32*2048*16
  int i4 = id & 15;
  int t = (id >> 4) & 2047;
  int bh = id >> 15;
  int idx0 = i4 * 4;
  size_t base = ((size_t)bh * TT + t) * HDD;
  bf16x4 x1 = *(const bf16x4*)(buf + base + idx0);
  bf16x4 x2 = *(const bf16x4*)(buf + base + 64 + idx0);
  float4 ct = *(const float4*)(cT + t * 64 + idx0);
  float4 st = *(const float4*)(sT + t * 64 + idx0);
  bf16x4 o1, o2;
  float c0, s0, a, b2;
#pragma unroll
  for (int j = 0; j < 4; ++j) {
    c0 = (j == 0) ? ct.x : (j == 1) ? ct.y : (j == 2) ? ct.z : ct.w;
    s0 = (j == 0) ? st.x : (j == 1) ? st.y : (j == 2) ? st.z : st.w;
    a = (float)x1[j];
    b2 = (float)x2[j];
    o1[j] = (bf16)(a * c0 - b2 * s0);
    o2[j] = (bf16)(a * s0 + b2 * c0);
  }
  *(bf16x4*)(buf + base + idx0) = o1;
  *(bf16x4*)(buf + base + 64 + idx0) = o2;
}

// ---------------------------------------------------------------- GEMM
// C(M,N) = A(M,K) * Bt(N,K)^T + bias.  128x128 tile, BK=64, 4 waves 2x2.
// XCD-aware bijective swizzle (nwg % 8 == 0 for both call sites).
template <int EPI>
__global__ __launch_bounds__(256, 2) void gemm_bt_k(
    const bf16* __restrict__ A, const bf16* __restrict__ Bt,
    const float* __restrict__ bias,
    bf16* __restrict__ q_out, bf16* __restrict__ k_out, bf16* __restrict__ v_out,
    float* __restrict__ c_out, int M, int N, int K) {
  __shared__ __align__(16) bf16 Asm[128 * 64];
  __shared__ __align__(16) bf16 Bsm[128 * 64];
  const int tid = threadIdx.x;
  const int w = tid >> 6, l = tid & 63;
  const int lane16 = l & 15, lgrp = l >> 4;
  const int wm = w >> 1, wn = w & 1;

  int flat = blockIdx.y * gridDim.x + blockIdx.x;
  {
    const int nwg = gridDim.x * gridDim.y;
    const int cpx = nwg >> 3;
    flat = (flat & 7) * cpx + (flat >> 3);
  }
  const int bm = flat % gridDim.x;
  const int bn = flat / gridDim.x;

  const int l8r = l >> 3, l8c = l & 7;

  f32x4 acc[4][4] = {};

  for (int k0 = 0; k0 < K; k0 += 64) {
    __syncthreads();
#pragma unroll
    for (int i = 0; i < 4; ++i) {
      int slot = w * 4 + i;
      int row = slot * 8 + l8r;
      gload_lds16(A + (size_t)(bm * 128 + row) * K + k0 + l8c * 8,
                  &Asm[slot * 512]);
      gload_lds16(Bt + (size_t)(bn * 128 + row) * K + k0 + l8c * 8,
                  &Bsm[slot * 512]);
    }
    __syncthreads();
#pragma unroll
    for (int kk = 0; kk < 2; ++kk) {
      bf16x8 af[4], bfr[4];
#pragma unroll
      for (int mf = 0; mf < 4; ++mf) {
        int row = wm * 64 + mf * 16 + lane16;
        af[mf] = *(const bf16x8*)&Asm[row * 64 + kk * 32 + lgrp * 8];
      }
#pragma unroll
      for (int nf = 0; nf < 4; ++nf) {
        int col = wn * 64 + nf * 16 + lane16;
        bfr[nf] = *(const bf16x8*)&Bsm[col * 64 + kk * 32 + lgrp * 8];
      }
#pragma unroll
      for (int mf = 0; mf < 4; ++mf)
#pragma unroll
        for (int nf = 0; nf < 4; ++nf)
          acc[mf][nf] = __builtin_amdgcn_mfma_f32_16x16x32_bf16(
              af[mf], bfr[nf], acc[mf][nf], 0, 0, 0);
    }
  }

  if (EPI == 0) {
    const int which = bn >> 4;
    const int head = bn & 15;
    bf16* outb = (which == 0) ? q_out : (which == 1 ? k_out : v_out);
#pragma unroll
    for (int nf = 0; nf < 4; ++nf) {
      int hd = wn * 64 + nf * 16 + lane16;
      float bv = bias[bn * 128 + hd];
#pragma unroll
      for (int mf = 0; mf < 4; ++mf)
#pragma unroll
        for (int r = 0; r < 4; ++r) {
          int row = bm * 128 + wm * 64 + mf * 16 + lgrp * 4 + r;
          int b = row >> 11, t = row & 2047;
          outb[((size_t)(b * NH + head) * TT + t) * HDD + hd] =
              (bf16)(acc[mf][nf][r] + bv);
        }
    }
  } else {
#pragma unroll
    for (int nf = 0; nf < 4; ++nf) {
      int colg = bn * 128 + wn * 64 + nf * 16 + lane16;
      float bv = bias[colg];
#pragma unroll
      for (int mf = 0; mf < 4; ++mf)
#pragma unroll
        for (int r = 0; r < 4; ++r) {
          int row = bm * 128 + wm * 64 + mf * 16 + lgrp * 4 + r;
          c_out[(size_t)row * N + colg] = acc[mf][nf][r] + bv;
        }
    }
  }
}

// ---------------------------------------------------------------- attention
// grid (8, B*H) = 256 blocks, 8 waves (512 thr); block does q-tiles
// {bx, 15-bx} (128 rows each) -> exactly 17 K-tiles of 128 keys per block.
// Wave w owns q-rows [q0 + 16w, q0 + 16w + 16).
// K staged via global_load_lds (pre-swizzled source, linear LDS dest,
// __syncthreads-fenced); V reg-staged + perm-transposed. 96KB LDS, 1 blk/CU.
__global__ __launch_bounds__(512, 2) void attn_k(
    const bf16* __restrict__ Q, const bf16* __restrict__ Kt,
    const bf16* __restrict__ V, bf16* __restrict__ Y) {
  __shared__ __align__(16) bf16 Ksm[128 * 128];   // [key][hd], chunk^=(key&7), 32KB
  __shared__ __align__(16) bf16 Vsm[128 * 128];   // [hd][key], chunk^=(hd&7), 32KB
  __shared__ __align__(16) bf16 Psm[8][16 * 128]; // per-wave P, chunk^=(row&7), 32KB
  const int tid = threadIdx.x, w = tid >> 6, l = tid & 63;
  const int lane16 = l & 15, lgrp = l >> 4;
  const int bh = blockIdx.y;
  const int b = bh >> 4, h = bh & 15;
  const size_t base = (size_t)bh * TT * HDD;

  uint4 vreg[4];
  const int vg = tid >> 4, vh8 = tid & 15;   // V staging coords (32 key-groups x 16)

  // V: load 4 keys x 8 hd per thread (issued FIRST so K-gloads overlap repack)
  auto load_V = [&](int k0) {
#pragma unroll
    for (int kq = 0; kq < 4; ++kq)
      vreg[kq] = *(const uint4*)(V + base + (size_t)(k0 + vg * 4 + kq) * HDD + vh8 * 8);
  };
  // K: direct-to-LDS, wave w covers keys w*16..+15; 4 chunks of 1KB.
  // LDS linear; global source chunk pre-swizzled: chunk' = chunk ^ (key&7).
  auto issue_K = [&](int k0) {
#pragma unroll
    for (int i = 0; i < 4; ++i) {
      int key = w * 16 + i * 4 + (l >> 4);
      int chunk = (l & 15) ^ (key & 7);
      gload_lds16(Kt + base + (size_t)(k0 + key) * HDD + chunk * 8,
                  &Ksm[(w * 16 + i * 4) * 128 + (l & 15) * 8]);
    }
  };
  auto write_V = [&]() {
    const unsigned* dw = (const unsigned*)vreg;
    int hd0 = vh8 * 8;
#pragma unroll
    for (int j = 0; j < 8; ++j) {
      int ww = j >> 1;
      unsigned sel = (j & 1) ? 0x07060302u : 0x05040100u;
      uint2 val;
      val.x = __builtin_amdgcn_perm(dw[4 + ww], dw[0 + ww], sel);   // keys vg*4+0,1
      val.y = __builtin_amdgcn_perm(dw[12 + ww], dw[8 + ww], sel);  // keys vg*4+2,3
      int hd = hd0 + j;
      int byte = hd * 256 + ((((vg >> 1) ^ (hd & 7)) << 4)) + ((vg & 1) << 3);
      *(uint2*)((char*)Vsm + byte) = val;
    }
  };

  for (int pass = 0; pass < 2; ++pass) {
    const int qt = (pass == 0) ? (int)blockIdx.x : 15 - (int)blockIdx.x;
    const int q0 = qt * 128;
    const int nt = qt + 1;     // 128-key tiles

    // Q fragments (registers)
    bf16x8 qa[4];
    {
      int row = q0 + w * 16 + lane16;
#pragma unroll
      for (int kk = 0; kk < 4; ++kk)
        qa[kk] = *(const bf16x8*)(Q + base + (size_t)row * HDD + kk * 32 + lgrp * 8);
    }

    f32x4 o[8] = {};
    float m_r[4], l_r[4];
#pragma unroll
    for (int r = 0; r < 4; ++r) { m_r[r] = NEG_INF; l_r[r] = 0.f; }

    for (int kt = 0; kt < nt; ++kt) {
      const int k0 = kt * 128;
      load_V(k0);           // V loads first (oldest in vmcnt queue)
      issue_K(k0);          // K direct-to-LDS, in flight during V repack
      write_V();            // waits only the 4 V loads; WAR safe (prev barrier)
      __syncthreads();      // drains vmcnt+lgkmcnt: K & V staged for all waves

      // ---- S = Q K^T  (16 q-rows x 128 keys per wave)
      f32x4 s[8] = {};
#pragma unroll
      for (int kk = 0; kk < 4; ++kk) {
#pragma unroll
        for (int nf = 0; nf < 8; ++nf) {
          int key = nf * 16 + lane16;
          int byte = key * 256 + ((((kk * 4 + lgrp) ^ (key & 7))) << 4);
          bf16x8 kf = *(const bf16x8*)((char*)Ksm + byte);
          s[nf] = __builtin_amdgcn_mfma_f32_16x16x32_bf16(
              qa[kk], kf, s[nf], 0, 0, 0);
        }
      }

      // ---- scale + causal mask (last tile is always the diagonal tile)
      const int rowbase = q0 + w * 16 + lgrp * 4;
      const bool needmask = (k0 + 127 > q0 + w * 16);
#pragma unroll
      for (int nf = 0; nf < 8; ++nf) {
        int col = k0 + nf * 16 + lane16;
#pragma unroll
        for (int r = 0; r < 4; ++r) {
          float sv = s[nf][r] * ATT_SCALE;
          if (needmask && col > rowbase + r) sv = -3.0e38f;
          s[nf][r] = sv;
        }
      }

      // ---- online softmax (R1-proven math, 8 frags)
#pragma unroll
      for (int r = 0; r < 4; ++r) {
        float tm = fmaxf(fmaxf(fmaxf(s[0][r], s[1][r]), fmaxf(s[2][r], s[3][r])),
                         fmaxf(fmaxf(s[4][r], s[5][r]), fmaxf(s[6][r], s[7][r])));
        tm = fmaxf(tm, __shfl_xor(tm, 1));
        tm = fmaxf(tm, __shfl_xor(tm, 2));
        tm = fmaxf(tm, __shfl_xor(tm, 4));
        tm = fmaxf(tm, __shfl_xor(tm, 8));
        float mo = m_r[r];
        float mn = fmaxf(mo, tm);
        float alpha = exp2f((mo - mn) * L2E);
        m_r[r] = mn;
        float rs = 0.f;
#pragma unroll
        for (int nf = 0; nf < 8; ++nf) {
          float p = exp2f((s[nf][r] - mn) * L2E);
          s[nf][r] = p;
          rs += p;
        }
        rs += __shfl_xor(rs, 1);
        rs += __shfl_xor(rs, 2);
        rs += __shfl_xor(rs, 4);
        rs += __shfl_xor(rs, 8);
        l_r[r] = l_r[r] * alpha + rs;
#pragma unroll
        for (int nf = 0; nf < 8; ++nf) o[nf][r] *= alpha;
      }

      // ---- P -> LDS (per-wave region, same-wave readback; no barrier)
#pragma unroll
      for (int nf = 0; nf < 8; ++nf)
#pragma unroll
        for (int r = 0; r < 4; ++r) {
          int rl = lgrp * 4 + r;
          int chunk = 2 * nf + (lane16 >> 3);
          int byte = rl * 256 + (((chunk ^ (rl & 7))) << 4) + ((lane16 & 7) << 1);
          *(bf16*)((char*)&Psm[w][0] + byte) = (bf16)s[nf][r];
        }
      bf16x8 pa[4];
#pragma unroll
      for (int kk = 0; kk < 4; ++kk) {
        int chunk = kk * 4 + lgrp;
        int byte = lane16 * 256 + (((chunk ^ (lane16 & 7))) << 4);
        pa[kk] = *(const bf16x8*)((char*)&Psm[w][0] + byte);
      }

      // ---- O += P V
#pragma unroll
      for (int nf = 0; nf < 8; ++nf) {
#pragma unroll
        for (int kk = 0; kk < 4; ++kk) {
          int hd = nf * 16 + lane16;
          int chunk = kk * 4 + lgrp;
          int byte = hd * 256 + (((chunk ^ (hd & 7))) << 4);
          bf16x8 vf = *(const bf16x8*)((char*)Vsm + byte);
          o[nf] = __builtin_amdgcn_mfma_f32_16x16x32_bf16(
              pa[kk], vf, o[nf], 0, 0, 0);
        }
      }

      __syncthreads();      // all waves done reading Ksm/Vsm before next stage
    }

    // ---- finalize: O / l -> Y (b,t,D) bf16
#pragma unroll
    for (int r = 0; r < 4; ++r) {
      float inv = 1.0f / l_r[r];
      int row = q0 + w * 16 + lgrp * 4 + r;
#pragma unroll
      for (int nf = 0; nf < 8; ++nf) {
        int hd = nf * 16 + lane16;
        Y[(size_t)(b * TT + row) * DM + h * HDD + hd] = (bf16)(o[nf][r] * inv);
      }
    }
  }
}

// ---------------------------------------------------------------- launch
extern "C" void kernel_launch(void* const* d_in, const int* in_sizes, int n_in,
                              void* d_out, int out_size, void* d_ws, size_t ws_size,
                              hipStream_t stream) {
  const float* x = (const float*)d_in[0];
  const float* Wqkv = (const float*)d_in[2];
  const float* bqkv = (const float*)d_in[3];
  const float* Wproj = (const float*)d_in[4];
  const float* bproj = (const float*)d_in[5];
  float* out = (float*)d_out;

  char* ws = (char*)d_ws;
  bf16* xb = (bf16*)ws;                 ws += (size_t)MM * DM * 2;
  bf16* Wqkvt = (bf16*)ws;              ws += (size_t)NQKV * DM * 2;
  bf16* Wprojt = (bf16*)ws;             ws += (size_t)DM * DM * 2;
  bf16* kb = (bf16*)ws;                 ws += (size_t)MM * DM * 2;
  bf16* vb = (bf16*)ws;                 ws += (size_t)MM * DM * 2;
  float* cosT = (float*)ws;             ws += (size_t)TT * 64 * 4;
  float* sinT = (float*)ws;             ws += (size_t)TT * 64 * 4;
  bf16* qb = (bf16*)d_out;              // q lives in d_out (overwritten by proj)
  bf16* yb = xb;                        // xb dead after QKV GEMM

  rope_table_k<<<dim3(512), dim3(256), 0, stream>>>(cosT, sinT);
  convert_x_k<<<dim3(4096), dim3(256), 0, stream>>>(x, xb);
  transpose_w_k<<<dim3(96, 32), dim3(256), 0, stream>>>(Wqkv, Wqkvt, DM, NQKV);
  transpose_w_k<<<dim3(32, 32), dim3(256), 0, stream>>>(Wproj, Wprojt, DM, DM);

  gemm_bt_k<0><<<dim3(32, 48), dim3(256), 0, stream>>>(
      xb, Wqkvt, bqkv, qb, kb, vb, nullptr, MM, NQKV, DM);

  rope_apply_k<<<dim3(4096), dim3(256), 0, stream>>>(qb, cosT, sinT);
  rope_apply_k<<<dim3(4096), dim3(256), 0, stream>>>(kb, cosT, sinT);

  attn_k<<<dim3(8, 32), dim3(512), 0, stream>>>(qb, kb, vb, yb);

  gemm_bt_k<1><<<dim3(32, 16), dim3(256), 0, stream>>>(
      yb, Wprojt, bproj, nullptr, nullptr, nullptr, out, MM, DM, DM);
}

// Round 6
// 327.564 us; speedup vs baseline: 1.9288x; 1.0159x over previous
//
#include <hip/hip_runtime.h>
#include <hip/hip_bf16.h>
#include <stdint.h>
#include <stddef.h>

typedef __bf16 bf16;
typedef __attribute__((ext_vector_type(8))) __bf16 bf16x8;
typedef __attribute__((ext_vector_type(4))) __bf16 bf16x4;
typedef __attribute__((ext_vector_type(4))) float f32x4;

#define DM 2048      // model dim
#define NH 16        // heads
#define HDD 128      // head dim
#define BB 2         // batch
#define TT 2048      // seq len
#define MM (BB*TT)   // 4096 rows
#define NQKV (3*DM)  // 6144

#define L2E 1.4426950408889634f
#define ATT_SCALE 0.08838834764831845f   // 1/sqrt(128)
#define NEG_INF (-__builtin_inff())

static_assert(sizeof(bf16x8) == 16, "bf16x8 must be 16B");

#define SB0() __builtin_amdgcn_sched_barrier(0)
#define WAITV6() { asm volatile("s_waitcnt vmcnt(6)" ::: "memory"); SB0(); }
#define WAITV0() { asm volatile("s_waitcnt vmcnt(0)" ::: "memory"); SB0(); }
#define WAITL0() { asm volatile("s_waitcnt lgkmcnt(0)" ::: "memory"); SB0(); }
#define BARRIER8() { SB0(); __builtin_amdgcn_s_barrier(); SB0(); }

// ---------------------------------------------------------------- helpers
static __device__ __forceinline__ void gload_lds16(const void* g, void* l) {
  __builtin_amdgcn_global_load_lds(
      (__attribute__((address_space(1))) void*)g,
      (__attribute__((address_space(3))) void*)l, 16, 0, 0);
}

// ---------------------------------------------------------------- pre-pass
__global__ __launch_bounds__(256) void rope_table_k(float* __restrict__ cT,
                                                    float* __restrict__ sT) {
  int id = blockIdx.x * 256 + threadIdx.x;          // < 2048*64
  int t = id >> 6, i = id & 63;
  float freq = powf(10000.0f, -(float)i * (1.0f / 64.0f));
  float theta = (float)t * freq;
  float s, c;
  __sincosf(theta, &s, &c);
  cT[id] = c;
  sT[id] = s;
}

__global__ __launch_bounds__(256) void convert_x_k(const float* __restrict__ x,
                                                   bf16* __restrict__ xb) {
  size_t id = (size_t)blockIdx.x * 256 + threadIdx.x;
  size_t o = id * 8;
  float4 a = *(const float4*)(x + o);
  float4 b = *(const float4*)(x + o + 4);
  bf16x8 r;
  r[0] = (bf16)a.x; r[1] = (bf16)a.y; r[2] = (bf16)a.z; r[3] = (bf16)a.w;
  r[4] = (bf16)b.x; r[5] = (bf16)b.y; r[6] = (bf16)b.z; r[7] = (bf16)b.w;
  *(bf16x8*)(xb + o) = r;
}

// W (K x N) f32 -> Wt (N x K) bf16, 64x64 tiles
__global__ __launch_bounds__(256) void transpose_w_k(const float* __restrict__ W,
                                                     bf16* __restrict__ Wt,
                                                     int K, int N) {
  __shared__ float tile[64][65];
  int n0 = blockIdx.x * 64, k0 = blockIdx.y * 64;
  int t = threadIdx.x;
#pragma unroll
  for (int i = 0; i < 16; ++i) {
    int idx = t + i * 256;
    int r = idx >> 6, c = idx & 63;
    tile[r][c] = W[(size_t)(k0 + r) * N + n0 + c];
  }
  __syncthreads();
#pragma unroll
  for (int i = 0; i < 16; ++i) {
    int idx = t + i * 256;
    int r = idx >> 6, c = idx & 63;
    Wt[(size_t)(n0 + r) * K + k0 + c] = (bf16)tile[c][r];
  }
}

// in-place RoPE on (b,h,t,hd) bf16 buffer; half-split style
__global__ __launch_bounds__(256) void rope_apply_k(bf16* __restrict__ buf,
                                                    const float* __restrict__ cT,
                                                    const float* __restrict__ sT) {
  int id = blockIdx.x * 256 + threadIdx.x;   // < 32*2048*16
  int i4 = id & 15;
  int t = (id >> 4) & 2047;
  int bh = id >> 15;
  int idx0 = i4 * 4;
  size_t base = ((size_t)bh * TT + t) * HDD;
  bf16x4 x1 = *(const bf16x4*)(buf + base + idx0);
  bf16x4 x2 = *(const bf16x4*)(buf + base + 64 + idx0);
  float4 ct = *(const float4*)(cT + t * 64 + idx0);
  float4 st = *(const float4*)(sT + t * 64 + idx0);
  bf16x4 o1, o2;
  float c0, s0, a, b2;
#pragma unroll
  for (int j = 0; j < 4; ++j) {
    c0 = (j == 0) ? ct.x : (j == 1) ? ct.y : (j == 2) ? ct.z : ct.w;
    s0 = (j == 0) ? st.x : (j == 1) ? st.y : (j == 2) ? st.z : st.w;
    a = (float)x1[j];
    b2 = (float)x2[j];
    o1[j] = (bf16)(a * c0 - b2 * s0);
    o2[j] = (bf16)(a * s0 + b2 * c0);
  }
  *(bf16x4*)(buf + base + idx0) = o1;
  *(bf16x4*)(buf + base + 64 + idx0) = o2;
}

// ---------------------------------------------------------------- GEMM (proj)
// C(M,N) = A(M,K) * Bt(N,K)^T + bias.  128x128 tile, BK=64, 4 waves 2x2.
template <int EPI>
__global__ __launch_bounds__(256, 2) void gemm_bt_k(
    const bf16* __restrict__ A, const bf16* __restrict__ Bt,
    const float* __restrict__ bias,
    bf16* __restrict__ q_out, bf16* __restrict__ k_out, bf16* __restrict__ v_out,
    float* __restrict__ c_out, int M, int N, int K) {
  __shared__ __align__(16) bf16 Asm[128 * 64];
  __shared__ __align__(16) bf16 Bsm[128 * 64];
  const int tid = threadIdx.x;
  const int w = tid >> 6, l = tid & 63;
  const int lane16 = l & 15, lgrp = l >> 4;
  const int wm = w >> 1, wn = w & 1;

  int flat = blockIdx.y * gridDim.x + blockIdx.x;
  {
    const int nwg = gridDim.x * gridDim.y;
    const int cpx = nwg >> 3;
    flat = (flat & 7) * cpx + (flat >> 3);
  }
  const int bm = flat % gridDim.x;
  const int bn = flat / gridDim.x;

  const int l8r = l >> 3, l8c = l & 7;

  f32x4 acc[4][4] = {};

  for (int k0 = 0; k0 < K; k0 += 64) {
    __syncthreads();
#pragma unroll
    for (int i = 0; i < 4; ++i) {
      int slot = w * 4 + i;
      int row = slot * 8 + l8r;
      gload_lds16(A + (size_t)(bm * 128 + row) * K + k0 + l8c * 8,
                  &Asm[slot * 512]);
      gload_lds16(Bt + (size_t)(bn * 128 + row) * K + k0 + l8c * 8,
                  &Bsm[slot * 512]);
    }
    __syncthreads();
#pragma unroll
    for (int kk = 0; kk < 2; ++kk) {
      bf16x8 af[4], bfr[4];
#pragma unroll
      for (int mf = 0; mf < 4; ++mf) {
        int row = wm * 64 + mf * 16 + lane16;
        af[mf] = *(const bf16x8*)&Asm[row * 64 + kk * 32 + lgrp * 8];
      }
#pragma unroll
      for (int nf = 0; nf < 4; ++nf) {
        int col = wn * 64 + nf * 16 + lane16;
        bfr[nf] = *(const bf16x8*)&Bsm[col * 64 + kk * 32 + lgrp * 8];
      }
#pragma unroll
      for (int mf = 0; mf < 4; ++mf)
#pragma unroll
        for (int nf = 0; nf < 4; ++nf)
          acc[mf][nf] = __builtin_amdgcn_mfma_f32_16x16x32_bf16(
              af[mf], bfr[nf], acc[mf][nf], 0, 0, 0);
    }
  }

  if (EPI == 0) {
    const int which = bn >> 4;
    const int head = bn & 15;
    bf16* outb = (which == 0) ? q_out : (which == 1 ? k_out : v_out);
#pragma unroll
    for (int nf = 0; nf < 4; ++nf) {
      int hd = wn * 64 + nf * 16 + lane16;
      float bv = bias[bn * 128 + hd];
#pragma unroll
      for (int mf = 0; mf < 4; ++mf)
#pragma unroll
        for (int r = 0; r < 4; ++r) {
          int row = bm * 128 + wm * 64 + mf * 16 + lgrp * 4 + r;
          int b = row >> 11, t = row & 2047;
          outb[((size_t)(b * NH + head) * TT + t) * HDD + hd] =
              (bf16)(acc[mf][nf][r] + bv);
        }
    }
  } else {
#pragma unroll
    for (int nf = 0; nf < 4; ++nf) {
      int colg = bn * 128 + wn * 64 + nf * 16 + lane16;
      float bv = bias[colg];
#pragma unroll
      for (int mf = 0; mf < 4; ++mf)
#pragma unroll
        for (int r = 0; r < 4; ++r) {
          int row = bm * 128 + wm * 64 + mf * 16 + lgrp * 4 + r;
          c_out[(size_t)row * N + colg] = acc[mf][nf][r] + bv;
        }
    }
  }
}

// ---------------------------------------------------------------- GEMM (QKV, 8-phase 256^2)
// 512 thr = 8 waves (2M x 4N); per-wave output 128x64; BK=64; 128KB LDS dbuf.
// T2 swizzle chunk^=(row&7) via pre-swizzled global src (linear LDS dest).
// Per K-tile: ph0 read all frags + stage t+1.B1 + MFMA Q0 | ph1 MFMA Q1 +
// lgkm0 | ph2 stage t+2.A0,A1 + MFMA Q2 | ph3 stage t+2.B0 + MFMA Q3 +
// vmcnt(6). Raw barriers between phases; vmcnt never 0 mid-loop.
#define MFMA_Q(MF0, NF0)                                                   \
  do {                                                                     \
    __builtin_amdgcn_s_setprio(1);                                         \
    _Pragma("unroll") for (int mf = 0; mf < 4; ++mf)                       \
    _Pragma("unroll") for (int nf = 0; nf < 2; ++nf)                       \
    _Pragma("unroll") for (int kk = 0; kk < 2; ++kk)                       \
      acc[(MF0) + mf][(NF0) + nf] = __builtin_amdgcn_mfma_f32_16x16x32_bf16( \
          af[(MF0) + mf][kk], bfr[(NF0) + nf][kk], acc[(MF0) + mf][(NF0) + nf], 0, 0, 0); \
    __builtin_amdgcn_s_setprio(0);                                         \
  } while (0)

__global__ __launch_bounds__(512, 2) void gemm8_qkv_k(
    const bf16* __restrict__ A, const bf16* __restrict__ Bt,
    const float* __restrict__ bias,
    bf16* __restrict__ q_out, bf16* __restrict__ k_out, bf16* __restrict__ v_out,
    int M, int N, int K) {
  __shared__ __align__(16) char Lsm[2][2][32768];   // [buf][A/B][256 rows x 128B]
  const int tid = threadIdx.x;
  const int wid = tid >> 6, l = tid & 63;
  const int lane16 = l & 15, lgrp = l >> 4;
  const int wm = wid >> 2, wn = wid & 3;

  int flat = blockIdx.y * gridDim.x + blockIdx.x;
  {
    const int cpx = (gridDim.x * gridDim.y) >> 3;
    flat = (flat & 7) * cpx + (flat >> 3);
  }
  const int bm = flat % gridDim.x;
  const int bn = flat / gridDim.x;
  const int NT = K >> 6;

  // staging: per half-tile (128 rows x 64 cols), wave slice (wid*2+i)*1KB.
  // LDS linear; lane l covers row = h*128+(wid*2+i)*8+(l>>3), chunk l&7.
  // Source chunk pre-swizzled: (l&7) ^ ((l>>3)&7)  [== chunk ^ (row&7)].
  const int srow = wid * 16 + (l >> 3);              // +8 for i=1
  const int schunk = (l & 7) ^ ((l >> 3) & 7);
  const bf16* gA = A + (size_t)(bm * 256) * K + schunk * 8;
  const bf16* gB = Bt + (size_t)(bn * 256) * K + schunk * 8;

  auto stage_half = [&](int mat, int t, int h, int buf) {
    const bf16* g = mat ? gB : gA;
#pragma unroll
    for (int i = 0; i < 2; ++i) {
      int row = h * 128 + srow + i * 8;
      gload_lds16(g + (size_t)row * K + t * 64,
                  &Lsm[buf][mat][h * 16384 + (wid * 2 + i) * 1024]);
    }
  };

  f32x4 acc[8][4] = {};

  // prologue: tile 0 all 4 halves; drain; barrier; tile 1 A0,A1,B0 in flight
  stage_half(0, 0, 0, 0); stage_half(0, 0, 1, 0);
  stage_half(1, 0, 0, 0); stage_half(1, 0, 1, 0);
  WAITV0();
  BARRIER8();
  stage_half(0, 1, 0, 1); stage_half(0, 1, 1, 1); stage_half(1, 1, 0, 1);

  for (int t = 0; t < NT; ++t) {
    const int cur = t & 1;
    const char* As = &Lsm[cur][0][0];
    const char* Bs = &Lsm[cur][1][0];
    bf16x8 af[8][2], bfr[4][2];

    // ---- phase 0: read all frags; stage t+1.B1 -> buf[cur^1]; MFMA Q0
#pragma unroll
    for (int mf = 0; mf < 8; ++mf)
#pragma unroll
      for (int kk = 0; kk < 2; ++kk) {
        int row = wm * 128 + mf * 16 + lane16;
        int ch = (kk * 4 + lgrp) ^ (lane16 & 7);
        af[mf][kk] = *(const bf16x8*)(As + row * 128 + ch * 16);
      }
#pragma unroll
    for (int nf = 0; nf < 4; ++nf)
#pragma unroll
      for (int kk = 0; kk < 2; ++kk) {
        int row = wn * 64 + nf * 16 + lane16;
        int ch = (kk * 4 + lgrp) ^ (lane16 & 7);
        bfr[nf][kk] = *(const bf16x8*)(Bs + row * 128 + ch * 16);
      }
    if (t + 1 < NT) stage_half(1, t + 1, 1, cur ^ 1);
    MFMA_Q(0, 0);
    BARRIER8();

    // ---- phase 1: MFMA Q1; all buf[cur] reads complete before barrier
    MFMA_Q(0, 2);
    WAITL0();
    BARRIER8();

    // ---- phase 2: stage t+2.A0,A1 -> buf[cur]; MFMA Q2
    if (t + 2 < NT) { stage_half(0, t + 2, 0, cur); stage_half(0, t + 2, 1, cur); }
    MFMA_Q(4, 0);
    BARRIER8();

    // ---- phase 3: stage t+2.B0 -> buf[cur]; MFMA Q3; counted vm-wait
    if (t + 2 < NT) stage_half(1, t + 2, 0, cur);
    MFMA_Q(4, 2);
    if (t + 2 < NT) { WAITV6(); } else { WAITV0(); }
    BARRIER8();
  }

  // ---- epilogue: bias + scatter to q/k/v (b,head,t,hd) bf16
#pragma unroll
  for (int nf = 0; nf < 4; ++nf) {
    int colg = bn * 256 + wn * 64 + nf * 16 + lane16;
    int which = colg >> 11;
    bf16* outb = (which == 0) ? q_out : (which == 1 ? k_out : v_out);
    int head = (colg >> 7) & 15, hd = colg & 127;
    float bv = bias[colg];
#pragma unroll
    for (int mf = 0; mf < 8; ++mf)
#pragma unroll
      for (int r = 0; r < 4; ++r) {
        int row = bm * 256 + wm * 128 + mf * 16 + lgrp * 4 + r;
        int bb = row >> 11, tt2 = row & 2047;
        outb[((size_t)(bb * NH + head) * TT + tt2) * HDD + hd] =
            (bf16)(acc[mf][nf][r] + bv);
      }
  }
}

// ---------------------------------------------------------------- attention
// grid (8, B*H) = 256 blocks, 8 waves (512 thr); block does q-tiles
// {bx, 15-bx} (128 rows each) -> exactly 17 K-tiles of 128 keys per block.
__global__ __launch_bounds__(512, 2) void attn_k(
    const bf16* __restrict__ Q, const bf16* __restrict__ Kt,
    const bf16* __restrict__ V, bf16* __restrict__ Y) {
  __shared__ __align__(16) bf16 Ksm[128 * 128];   // [key][hd], chunk^=(key&7), 32KB
  __shared__ __align__(16) bf16 Vsm[128 * 128];   // [hd][key], chunk^=(hd&7), 32KB
  __shared__ __align__(16) bf16 Psm[8][16 * 128]; // per-wave P, chunk^=(row&7), 32KB
  const int tid = threadIdx.x, w = tid >> 6, l = tid & 63;
  const int lane16 = l & 15, lgrp = l >> 4;
  const int bh = blockIdx.y;
  const int b = bh >> 4, h = bh & 15;
  const size_t base = (size_t)bh * TT * HDD;

  uint4 vreg[4];
  const int vg = tid >> 4, vh8 = tid & 15;

  auto load_V = [&](int k0) {
#pragma unroll
    for (int kq = 0; kq < 4; ++kq)
      vreg[kq] = *(const uint4*)(V + base + (size_t)(k0 + vg * 4 + kq) * HDD + vh8 * 8);
  };
  auto issue_K = [&](int k0) {
#pragma unroll
    for (int i = 0; i < 4; ++i) {
      int key = w * 16 + i * 4 + (l >> 4);
      int chunk = (l & 15) ^ (key & 7);
      gload_lds16(Kt + base + (size_t)(k0 + key) * HDD + chunk * 8,
                  &Ksm[(w * 16 + i * 4) * 128 + (l & 15) * 8]);
    }
  };
  auto write_V = [&]() {
    const unsigned* dw = (const unsigned*)vreg;
    int hd0 = vh8 * 8;
#pragma unroll
    for (int j = 0; j < 8; ++j) {
      int ww = j >> 1;
      unsigned sel = (j & 1) ? 0x07060302u : 0x05040100u;
      uint2 val;
      val.x = __builtin_amdgcn_perm(dw[4 + ww], dw[0 + ww], sel);
      val.y = __builtin_amdgcn_perm(dw[12 + ww], dw[8 + ww], sel);
      int hd = hd0 + j;
      int byte = hd * 256 + ((((vg >> 1) ^ (hd & 7)) << 4)) + ((vg & 1) << 3);
      *(uint2*)((char*)Vsm + byte) = val;
    }
  };

  for (int pass = 0; pass < 2; ++pass) {
    const int qt = (pass == 0) ? (int)blockIdx.x : 15 - (int)blockIdx.x;
    const int q0 = qt * 128;
    const int nt = qt + 1;

    bf16x8 qa[4];
    {
      int row = q0 + w * 16 + lane16;
#pragma unroll
      for (int kk = 0; kk < 4; ++kk)
        qa[kk] = *(const bf16x8*)(Q + base + (size_t)row * HDD + kk * 32 + lgrp * 8);
    }

    f32x4 o[8] = {};
    float m_r[4], l_r[4];
#pragma unroll
    for (int r = 0; r < 4; ++r) { m_r[r] = NEG_INF; l_r[r] = 0.f; }

    for (int kt = 0; kt < nt; ++kt) {
      const int k0 = kt * 128;
      load_V(k0);
      issue_K(k0);
      write_V();
      __syncthreads();

      f32x4 s[8] = {};
#pragma unroll
      for (int kk = 0; kk < 4; ++kk) {
#pragma unroll
        for (int nf = 0; nf < 8; ++nf) {
          int key = nf * 16 + lane16;
          int byte = key * 256 + ((((kk * 4 + lgrp) ^ (key & 7))) << 4);
          bf16x8 kf = *(const bf16x8*)((char*)Ksm + byte);
          s[nf] = __builtin_amdgcn_mfma_f32_16x16x32_bf16(
              qa[kk], kf, s[nf], 0, 0, 0);
        }
      }

      const int rowbase = q0 + w * 16 + lgrp * 4;
      const bool needmask = (k0 + 127 > q0 + w * 16);
#pragma unroll
      for (int nf = 0; nf < 8; ++nf) {
        int col = k0 + nf * 16 + lane16;
#pragma unroll
        for (int r = 0; r < 4; ++r) {
          float sv = s[nf][r] * ATT_SCALE;
          if (needmask && col > rowbase + r) sv = -3.0e38f;
          s[nf][r] = sv;
        }
      }

#pragma unroll
      for (int r = 0; r < 4; ++r) {
        float tm = fmaxf(fmaxf(fmaxf(s[0][r], s[1][r]), fmaxf(s[2][r], s[3][r])),
                         fmaxf(fmaxf(s[4][r], s[5][r]), fmaxf(s[6][r], s[7][r])));
        tm = fmaxf(tm, __shfl_xor(tm, 1));
        tm = fmaxf(tm, __shfl_xor(tm, 2));
        tm = fmaxf(tm, __shfl_xor(tm, 4));
        tm = fmaxf(tm, __shfl_xor(tm, 8));
        float mo = m_r[r];
        float mn = fmaxf(mo, tm);
        float alpha = exp2f((mo - mn) * L2E);
        m_r[r] = mn;
        float rs = 0.f;
#pragma unroll
        for (int nf = 0; nf < 8; ++nf) {
          float p = exp2f((s[nf][r] - mn) * L2E);
          s[nf][r] = p;
          rs += p;
        }
        rs += __shfl_xor(rs, 1);
        rs += __shfl_xor(rs, 2);
        rs += __shfl_xor(rs, 4);
        rs += __shfl_xor(rs, 8);
        l_r[r] = l_r[r] * alpha + rs;
#pragma unroll
        for (int nf = 0; nf < 8; ++nf) o[nf][r] *= alpha;
      }

#pragma unroll
      for (int nf = 0; nf < 8; ++nf)
#pragma unroll
        for (int r = 0; r < 4; ++r) {
          int rl = lgrp * 4 + r;
          int chunk = 2 * nf + (lane16 >> 3);
          int byte = rl * 256 + (((chunk ^ (rl & 7))) << 4) + ((lane16 & 7) << 1);
          *(bf16*)((char*)&Psm[w][0] + byte) = (bf16)s[nf][r];
        }
      bf16x8 pa[4];
#pragma unroll
      for (int kk = 0; kk < 4; ++kk) {
        int chunk = kk * 4 + lgrp;
        int byte = lane16 * 256 + (((chunk ^ (lane16 & 7))) << 4);
        pa[kk] = *(const bf16x8*)((char*)&Psm[w][0] + byte);
      }

#pragma unroll
      for (int nf = 0; nf < 8; ++nf) {
#pragma unroll
        for (int kk = 0; kk < 4; ++kk) {
          int hd = nf * 16 + lane16;
          int chunk = kk * 4 + lgrp;
          int byte = hd * 256 + (((chunk ^ (hd & 7))) << 4);
          bf16x8 vf = *(const bf16x8*)((char*)Vsm + byte);
          o[nf] = __builtin_amdgcn_mfma_f32_16x16x32_bf16(
              pa[kk], vf, o[nf], 0, 0, 0);
        }
      }

      __syncthreads();
    }

#pragma unroll
    for (int r = 0; r < 4; ++r) {
      float inv = 1.0f / l_r[r];
      int row = q0 + w * 16 + lgrp * 4 + r;
#pragma unroll
      for (int nf = 0; nf < 8; ++nf) {
        int hd = nf * 16 + lane16;
        Y[(size_t)(b * TT + row) * DM + h * HDD + hd] = (bf16)(o[nf][r] * inv);
      }
    }
  }
}

// ---------------------------------------------------------------- launch
extern "C" void kernel_launch(void* const* d_in, const int* in_sizes, int n_in,
                              void* d_out, int out_size, void* d_ws, size_t ws_size,
                              hipStream_t stream) {
  const float* x = (const float*)d_in[0];
  const float* Wqkv = (const float*)d_in[2];
  const float* bqkv = (const float*)d_in[3];
  const float* Wproj = (const float*)d_in[4];
  const float* bproj = (const float*)d_in[5];
  float* out = (float*)d_out;

  char* ws = (char*)d_ws;
  bf16* xb = (bf16*)ws;                 ws += (size_t)MM * DM * 2;
  bf16* Wqkvt = (bf16*)ws;              ws += (size_t)NQKV * DM * 2;
  bf16* Wprojt = (bf16*)ws;             ws += (size_t)DM * DM * 2;
  bf16* kb = (bf16*)ws;                 ws += (size_t)MM * DM * 2;
  bf16* vb = (bf16*)ws;                 ws += (size_t)MM * DM * 2;
  float* cosT = (float*)ws;             ws += (size_t)TT * 64 * 4;
  float* sinT = (float*)ws;             ws += (size_t)TT * 64 * 4;
  bf16* qb = (bf16*)d_out;              // q lives in d_out (overwritten by proj)
  bf16* yb = xb;                        // xb dead after QKV GEMM

  rope_table_k<<<dim3(512), dim3(256), 0, stream>>>(cosT, sinT);
  convert_x_k<<<dim3(4096), dim3(256), 0, stream>>>(x, xb);
  transpose_w_k<<<dim3(96, 32), dim3(256), 0, stream>>>(Wqkv, Wqkvt, DM, NQKV);
  transpose_w_k<<<dim3(32, 32), dim3(256), 0, stream>>>(Wproj, Wprojt, DM, DM);

  gemm8_qkv_k<<<dim3(16, 24), dim3(512), 0, stream>>>(
      xb, Wqkvt, bqkv, qb, kb, vb, MM, NQKV, DM);

  rope_apply_k<<<dim3(4096), dim3(256), 0, stream>>>(qb, cosT, sinT);
  rope_apply_k<<<dim3(4096), dim3(256), 0, stream>>>(kb, cosT, sinT);

  attn_k<<<dim3(8, 32), dim3(512), 0, stream>>>(qb, kb, vb, yb);

  gemm_bt_k<1><<<dim3(32, 16), dim3(256), 0, stream>>>(
      yb, Wprojt, bproj, nullptr, nullptr, nullptr, out, MM, DM, DM);
}

// Round 7
// 303.831 us; speedup vs baseline: 2.0795x; 1.0781x over previous
//
#include <hip/hip_runtime.h>
#include <hip/hip_bf16.h>
#include <stdint.h>
#include <stddef.h>

typedef __bf16 bf16;
typedef __attribute__((ext_vector_type(8))) __bf16 bf16x8;
typedef __attribute__((ext_vector_type(4))) __bf16 bf16x4;
typedef __attribute__((ext_vector_type(4))) float f32x4;

#define DM 2048      // model dim
#define NH 16        // heads
#define HDD 128      // head dim
#define BB 2         // batch
#define TT 2048      // seq len
#define MM (BB*TT)   // 4096 rows
#define NQKV (3*DM)  // 6144

#define L2E 1.4426950408889634f
#define ATT_SCALE 0.08838834764831845f   // 1/sqrt(128)
#define NEG_INF (-__builtin_inff())

static_assert(sizeof(bf16x8) == 16, "bf16x8 must be 16B");

#define SB0() __builtin_amdgcn_sched_barrier(0)
#define WAITV0() { asm volatile("s_waitcnt vmcnt(0)" ::: "memory"); SB0(); }
#define WAITL0() { asm volatile("s_waitcnt lgkmcnt(0)" ::: "memory"); SB0(); }
#define BARRIER8() { SB0(); __builtin_amdgcn_s_barrier(); SB0(); }

// ---------------------------------------------------------------- helpers
static __device__ __forceinline__ void gload_lds16(const void* g, void* l) {
  __builtin_amdgcn_global_load_lds(
      (__attribute__((address_space(1))) void*)g,
      (__attribute__((address_space(3))) void*)l, 16, 0, 0);
}

// ---------------------------------------------------------------- pre-pass
__global__ __launch_bounds__(256) void rope_table_k(float* __restrict__ cT,
                                                    float* __restrict__ sT) {
  int id = blockIdx.x * 256 + threadIdx.x;          // < 2048*64
  int t = id >> 6, i = id & 63;
  float freq = powf(10000.0f, -(float)i * (1.0f / 64.0f));
  float theta = (float)t * freq;
  float s, c;
  __sincosf(theta, &s, &c);
  cT[id] = c;
  sT[id] = s;
}

__global__ __launch_bounds__(256) void convert_x_k(const float* __restrict__ x,
                                                   bf16* __restrict__ xb) {
  size_t id = (size_t)blockIdx.x * 256 + threadIdx.x;
  size_t o = id * 8;
  float4 a = *(const float4*)(x + o);
  float4 b = *(const float4*)(x + o + 4);
  bf16x8 r;
  r[0] = (bf16)a.x; r[1] = (bf16)a.y; r[2] = (bf16)a.z; r[3] = (bf16)a.w;
  r[4] = (bf16)b.x; r[5] = (bf16)b.y; r[6] = (bf16)b.z; r[7] = (bf16)b.w;
  *(bf16x8*)(xb + o) = r;
}

// W (K x N) f32 -> Wt (N x K) bf16, 64x64 tiles
__global__ __launch_bounds__(256) void transpose_w_k(const float* __restrict__ W,
                                                     bf16* __restrict__ Wt,
                                                     int K, int N) {
  __shared__ float tile[64][65];
  int n0 = blockIdx.x * 64, k0 = blockIdx.y * 64;
  int t = threadIdx.x;
#pragma unroll
  for (int i = 0; i < 16; ++i) {
    int idx = t + i * 256;
    int r = idx >> 6, c = idx & 63;
    tile[r][c] = W[(size_t)(k0 + r) * N + n0 + c];
  }
  __syncthreads();
#pragma unroll
  for (int i = 0; i < 16; ++i) {
    int idx = t + i * 256;
    int r = idx >> 6, c = idx & 63;
    Wt[(size_t)(n0 + r) * K + k0 + c] = (bf16)tile[c][r];
  }
}

// in-place RoPE on (b,h,t,hd) bf16 buffer; half-split style
__global__ __launch_bounds__(256) void rope_apply_k(bf16* __restrict__ buf,
                                                    const float* __restrict__ cT,
                                                    const float* __restrict__ sT) {
  int id = blockIdx.x * 256 + threadIdx.x;   // < 32*2048*16
  int i4 = id & 15;
  int t = (id >> 4) & 2047;
  int bh = id >> 15;
  int idx0 = i4 * 4;
  size_t base = ((size_t)bh * TT + t) * HDD;
  bf16x4 x1 = *(const bf16x4*)(buf + base + idx0);
  bf16x4 x2 = *(const bf16x4*)(buf + base + 64 + idx0);
  float4 ct = *(const float4*)(cT + t * 64 + idx0);
  float4 st = *(const float4*)(sT + t * 64 + idx0);
  bf16x4 o1, o2;
  float c0, s0, a, b2;
#pragma unroll
  for (int j = 0; j < 4; ++j) {
    c0 = (j == 0) ? ct.x : (j == 1) ? ct.y : (j == 2) ? ct.z : ct.w;
    s0 = (j == 0) ? st.x : (j == 1) ? st.y : (j == 2) ? st.z : st.w;
    a = (float)x1[j];
    b2 = (float)x2[j];
    o1[j] = (bf16)(a * c0 - b2 * s0);
    o2[j] = (bf16)(a * s0 + b2 * c0);
  }
  *(bf16x4*)(buf + base + idx0) = o1;
  *(bf16x4*)(buf + base + 64 + idx0) = o2;
}

// ---------------------------------------------------------------- GEMM (proj)
// C(M,N) = A(M,K) * Bt(N,K)^T + bias.  128x128 tile, BK=64, 4 waves 2x2.
template <int EPI>
__global__ __launch_bounds__(256, 2) void gemm_bt_k(
    const bf16* __restrict__ A, const bf16* __restrict__ Bt,
    const float* __restrict__ bias,
    bf16* __restrict__ q_out, bf16* __restrict__ k_out, bf16* __restrict__ v_out,
    float* __restrict__ c_out, int M, int N, int K) {
  __shared__ __align__(16) bf16 Asm[128 * 64];
  __shared__ __align__(16) bf16 Bsm[128 * 64];
  const int tid = threadIdx.x;
  const int w = tid >> 6, l = tid & 63;
  const int lane16 = l & 15, lgrp = l >> 4;
  const int wm = w >> 1, wn = w & 1;

  int flat = blockIdx.y * gridDim.x + blockIdx.x;
  {
    const int nwg = gridDim.x * gridDim.y;
    const int cpx = nwg >> 3;
    flat = (flat & 7) * cpx + (flat >> 3);
  }
  const int bm = flat % gridDim.x;
  const int bn = flat / gridDim.x;

  const int l8r = l >> 3, l8c = l & 7;

  f32x4 acc[4][4] = {};

  for (int k0 = 0; k0 < K; k0 += 64) {
    __syncthreads();
#pragma unroll
    for (int i = 0; i < 4; ++i) {
      int slot = w * 4 + i;
      int row = slot * 8 + l8r;
      gload_lds16(A + (size_t)(bm * 128 + row) * K + k0 + l8c * 8,
                  &Asm[slot * 512]);
      gload_lds16(Bt + (size_t)(bn * 128 + row) * K + k0 + l8c * 8,
                  &Bsm[slot * 512]);
    }
    __syncthreads();
#pragma unroll
    for (int kk = 0; kk < 2; ++kk) {
      bf16x8 af[4], bfr[4];
#pragma unroll
      for (int mf = 0; mf < 4; ++mf) {
        int row = wm * 64 + mf * 16 + lane16;
        af[mf] = *(const bf16x8*)&Asm[row * 64 + kk * 32 + lgrp * 8];
      }
#pragma unroll
      for (int nf = 0; nf < 4; ++nf) {
        int col = wn * 64 + nf * 16 + lane16;
        bfr[nf] = *(const bf16x8*)&Bsm[col * 64 + kk * 32 + lgrp * 8];
      }
#pragma unroll
      for (int mf = 0; mf < 4; ++mf)
#pragma unroll
        for (int nf = 0; nf < 4; ++nf)
          acc[mf][nf] = __builtin_amdgcn_mfma_f32_16x16x32_bf16(
              af[mf], bfr[nf], acc[mf][nf], 0, 0, 0);
    }
  }

  if (EPI == 0) {
    const int which = bn >> 4;
    const int head = bn & 15;
    bf16* outb = (which == 0) ? q_out : (which == 1 ? k_out : v_out);
#pragma unroll
    for (int nf = 0; nf < 4; ++nf) {
      int hd = wn * 64 + nf * 16 + lane16;
      float bv = bias[bn * 128 + hd];
#pragma unroll
      for (int mf = 0; mf < 4; ++mf)
#pragma unroll
        for (int r = 0; r < 4; ++r) {
          int row = bm * 128 + wm * 64 + mf * 16 + lgrp * 4 + r;
          int b = row >> 11, t = row & 2047;
          outb[((size_t)(b * NH + head) * TT + t) * HDD + hd] =
              (bf16)(acc[mf][nf][r] + bv);
        }
    }
  } else {
#pragma unroll
    for (int nf = 0; nf < 4; ++nf) {
      int colg = bn * 128 + wn * 64 + nf * 16 + lane16;
      float bv = bias[colg];
#pragma unroll
      for (int mf = 0; mf < 4; ++mf)
#pragma unroll
        for (int r = 0; r < 4; ++r) {
          int row = bm * 128 + wm * 64 + mf * 16 + lgrp * 4 + r;
          c_out[(size_t)row * N + colg] = acc[mf][nf][r] + bv;
        }
    }
  }
}

// ---------------------------------------------------------------- GEMM (QKV, 4-phase 256x192)
// 512 thr = 8 waves (2M x 4N); per-wave output 128x48; BK=64; 112KB LDS dbuf.
// grid 16x32 = 512 blocks = exactly 2 rounds at 1 block/CU (zero tail).
// T2 swizzle chunk^=(row&7) via pre-swizzled global src (linear LDS dest).
// Staging: 64-row units (A:4, B:3), one gload_lds16/wave/unit, depth-1
// prefetch into buf^1 during ph0/ph1. Every phase ends lgkm-drained, so
// buf^1 writes never race prior-tile reads.
#define MFMA_Q(MF0, NF0, NCNT)                                             \
  do {                                                                     \
    __builtin_amdgcn_s_setprio(1);                                         \
    _Pragma("unroll") for (int mf = 0; mf < 4; ++mf)                       \
    _Pragma("unroll") for (int nf = 0; nf < (NCNT); ++nf)                  \
    _Pragma("unroll") for (int kk = 0; kk < 2; ++kk)                       \
      acc[(MF0) + mf][(NF0) + nf] = __builtin_amdgcn_mfma_f32_16x16x32_bf16( \
          af[(MF0) + mf][kk], bfr[(NF0) + nf][kk], acc[(MF0) + mf][(NF0) + nf], 0, 0, 0); \
    __builtin_amdgcn_s_setprio(0);                                         \
  } while (0)

__global__ __launch_bounds__(512, 2) void gemm8_qkv_k(
    const bf16* __restrict__ A, const bf16* __restrict__ Bt,
    const float* __restrict__ bias,
    bf16* __restrict__ q_out, bf16* __restrict__ k_out, bf16* __restrict__ v_out,
    int M, int N, int K) {
  __shared__ __align__(16) char Lsm[2][57344];   // [buf][A:32KB | B:24KB]
  const int tid = threadIdx.x;
  const int wid = tid >> 6, l = tid & 63;
  const int lane16 = l & 15, lgrp = l >> 4;
  const int wm = wid >> 2, wn = wid & 3;

  int flat = blockIdx.y * gridDim.x + blockIdx.x;
  {
    const int cpx = (gridDim.x * gridDim.y) >> 3;
    flat = (flat & 7) * cpx + (flat >> 3);
  }
  const int bm = flat % gridDim.x;       // 0..15  (M/256)
  const int bn = flat / gridDim.x;       // 0..31  (N/192)
  const int NT = K >> 6;

  // staging geometry: unit = 64 rows x 64 cols (8KB). Wave w covers rows
  // [u*64 + w*8, +8); lane l -> row +(l>>3), LDS chunk l&7 (linear dest),
  // global source chunk (l&7)^((l>>3)&7)  [involution chunk^(row&7)].
  const int schunk = (l & 7) ^ ((l >> 3) & 7);
  const bf16* gA = A + (size_t)(bm * 256 + wid * 8 + (l >> 3)) * K + schunk * 8;
  const bf16* gB = Bt + (size_t)(bn * 192 + wid * 8 + (l >> 3)) * K + schunk * 8;

  auto stage_unit = [&](int mat, int t, int u, int buf) {
    const bf16* g = (mat ? gB : gA) + (size_t)(u * 64) * K + t * 64;
    gload_lds16(g, &Lsm[buf][(mat ? 32768 : 0) + u * 8192 + wid * 1024]);
  };

  f32x4 acc[8][3] = {};

  // prologue: all 7 units of tile 0 -> buf0
#pragma unroll
  for (int u = 0; u < 4; ++u) stage_unit(0, 0, u, 0);
#pragma unroll
  for (int u = 0; u < 3; ++u) stage_unit(1, 0, u, 0);

  for (int t = 0; t < NT; ++t) {
    const int cur = t & 1;
    const char* As = &Lsm[cur][0];
    const char* Bs = &Lsm[cur][32768];
    bf16x8 af[8][2], bfr[3][2];

    WAITV0();                    // this tile's 7 stage loads landed
    BARRIER8();                  // visible to all waves

    // ---- phase 0: read af[0..3]+bfr[0..1]; stage t+1 A-units; MFMA Q0
#pragma unroll
    for (int mf = 0; mf < 4; ++mf)
#pragma unroll
      for (int kk = 0; kk < 2; ++kk) {
        int row = wm * 128 + mf * 16 + lane16;
        int ch = (kk * 4 + lgrp) ^ (lane16 & 7);
        af[mf][kk] = *(const bf16x8*)(As + row * 128 + ch * 16);
      }
#pragma unroll
    for (int nf = 0; nf < 2; ++nf)
#pragma unroll
      for (int kk = 0; kk < 2; ++kk) {
        int row = wn * 48 + nf * 16 + lane16;
        int ch = (kk * 4 + lgrp) ^ (lane16 & 7);
        bfr[nf][kk] = *(const bf16x8*)(Bs + row * 128 + ch * 16);
      }
    if (t + 1 < NT) {
#pragma unroll
      for (int u = 0; u < 4; ++u) stage_unit(0, t + 1, u, cur ^ 1);
    }
    WAITL0();
    MFMA_Q(0, 0, 2);
    BARRIER8();

    // ---- phase 1: read af[4..7]+bfr[2]; stage t+1 B-units; MFMA Q1
#pragma unroll
    for (int mf = 4; mf < 8; ++mf)
#pragma unroll
      for (int kk = 0; kk < 2; ++kk) {
        int row = wm * 128 + mf * 16 + lane16;
        int ch = (kk * 4 + lgrp) ^ (lane16 & 7);
        af[mf][kk] = *(const bf16x8*)(As + row * 128 + ch * 16);
      }
#pragma unroll
    for (int kk = 0; kk < 2; ++kk) {
      int row = wn * 48 + 32 + lane16;
      int ch = (kk * 4 + lgrp) ^ (lane16 & 7);
      bfr[2][kk] = *(const bf16x8*)(Bs + row * 128 + ch * 16);
    }
    if (t + 1 < NT) {
#pragma unroll
      for (int u = 0; u < 3; ++u) stage_unit(1, t + 1, u, cur ^ 1);
    }
    WAITL0();
    MFMA_Q(0, 2, 1);
    BARRIER8();

    // ---- phase 2: MFMA Q2 (no LDS traffic)
    MFMA_Q(4, 0, 2);
    BARRIER8();

    // ---- phase 3: MFMA Q3; loop-top WAITV0+BARRIER closes the tile
    MFMA_Q(4, 2, 1);
  }

  // ---- epilogue: bias + scatter to q/k/v (b,head,t,hd) bf16
#pragma unroll
  for (int nf = 0; nf < 3; ++nf) {
    int colg = bn * 192 + wn * 48 + nf * 16 + lane16;
    int which = colg >> 11;
    bf16* outb = (which == 0) ? q_out : (which == 1 ? k_out : v_out);
    int head = (colg >> 7) & 15, hd = colg & 127;
    float bv = bias[colg];
#pragma unroll
    for (int mf = 0; mf < 8; ++mf)
#pragma unroll
      for (int r = 0; r < 4; ++r) {
        int row = bm * 256 + wm * 128 + mf * 16 + lgrp * 4 + r;
        int bb = row >> 11, tt2 = row & 2047;
        outb[((size_t)(bb * NH + head) * TT + tt2) * HDD + hd] =
            (bf16)(acc[mf][nf][r] + bv);
      }
  }
}

// ---------------------------------------------------------------- attention
// grid (8, B*H) = 256 blocks, 8 waves (512 thr); block does q-tiles
// {bx, 15-bx} (128 rows each) -> exactly 17 K-tiles of 128 keys per block.
__global__ __launch_bounds__(512, 2) void attn_k(
    const bf16* __restrict__ Q, const bf16* __restrict__ Kt,
    const bf16* __restrict__ V, bf16* __restrict__ Y) {
  __shared__ __align__(16) bf16 Ksm[128 * 128];   // [key][hd], chunk^=(key&7), 32KB
  __shared__ __align__(16) bf16 Vsm[128 * 128];   // [hd][key], chunk^=(hd&7), 32KB
  __shared__ __align__(16) bf16 Psm[8][16 * 128]; // per-wave P, chunk^=(row&7), 32KB
  const int tid = threadIdx.x, w = tid >> 6, l = tid & 63;
  const int lane16 = l & 15, lgrp = l >> 4;
  const int bh = blockIdx.y;
  const int b = bh >> 4, h = bh & 15;
  const size_t base = (size_t)bh * TT * HDD;

  uint4 vreg[4];
  const int vg = tid >> 4, vh8 = tid & 15;

  auto load_V = [&](int k0) {
#pragma unroll
    for (int kq = 0; kq < 4; ++kq)
      vreg[kq] = *(const uint4*)(V + base + (size_t)(k0 + vg * 4 + kq) * HDD + vh8 * 8);
  };
  auto issue_K = [&](int k0) {
#pragma unroll
    for (int i = 0; i < 4; ++i) {
      int key = w * 16 + i * 4 + (l >> 4);
      int chunk = (l & 15) ^ (key & 7);
      gload_lds16(Kt + base + (size_t)(k0 + key) * HDD + chunk * 8,
                  &Ksm[(w * 16 + i * 4) * 128 + (l & 15) * 8]);
    }
  };
  auto write_V = [&]() {
    const unsigned* dw = (const unsigned*)vreg;
    int hd0 = vh8 * 8;
#pragma unroll
    for (int j = 0; j < 8; ++j) {
      int ww = j >> 1;
      unsigned sel = (j & 1) ? 0x07060302u : 0x05040100u;
      uint2 val;
      val.x = __builtin_amdgcn_perm(dw[4 + ww], dw[0 + ww], sel);
      val.y = __builtin_amdgcn_perm(dw[12 + ww], dw[8 + ww], sel);
      int hd = hd0 + j;
      int byte = hd * 256 + ((((vg >> 1) ^ (hd & 7)) << 4)) + ((vg & 1) << 3);
      *(uint2*)((char*)Vsm + byte) = val;
    }
  };

  for (int pass = 0; pass < 2; ++pass) {
    const int qt = (pass == 0) ? (int)blockIdx.x : 15 - (int)blockIdx.x;
    const int q0 = qt * 128;
    const int nt = qt + 1;

    bf16x8 qa[4];
    {
      int row = q0 + w * 16 + lane16;
#pragma unroll
      for (int kk = 0; kk < 4; ++kk)
        qa[kk] = *(const bf16x8*)(Q + base + (size_t)row * HDD + kk * 32 + lgrp * 8);
    }

    f32x4 o[8] = {};
    float m_r[4], l_r[4];
#pragma unroll
    for (int r = 0; r < 4; ++r) { m_r[r] = NEG_INF; l_r[r] = 0.f; }

    for (int kt = 0; kt < nt; ++kt) {
      const int k0 = kt * 128;
      load_V(k0);
      issue_K(k0);
      write_V();
      __syncthreads();

      f32x4 s[8] = {};
#pragma unroll
      for (int kk = 0; kk < 4; ++kk) {
#pragma unroll
        for (int nf = 0; nf < 8; ++nf) {
          int key = nf * 16 + lane16;
          int byte = key * 256 + ((((kk * 4 + lgrp) ^ (key & 7))) << 4);
          bf16x8 kf = *(const bf16x8*)((char*)Ksm + byte);
          s[nf] = __builtin_amdgcn_mfma_f32_16x16x32_bf16(
              qa[kk], kf, s[nf], 0, 0, 0);
        }
      }

      const int rowbase = q0 + w * 16 + lgrp * 4;
      const bool needmask = (k0 + 127 > q0 + w * 16);
#pragma unroll
      for (int nf = 0; nf < 8; ++nf) {
        int col = k0 + nf * 16 + lane16;
#pragma unroll
        for (int r = 0; r < 4; ++r) {
          float sv = s[nf][r] * ATT_SCALE;
          if (needmask && col > rowbase + r) sv = -3.0e38f;
          s[nf][r] = sv;
        }
      }

#pragma unroll
      for (int r = 0; r < 4; ++r) {
        float tm = fmaxf(fmaxf(fmaxf(s[0][r], s[1][r]), fmaxf(s[2][r], s[3][r])),
                         fmaxf(fmaxf(s[4][r], s[5][r]), fmaxf(s[6][r], s[7][r])));
        tm = fmaxf(tm, __shfl_xor(tm, 1));
        tm = fmaxf(tm, __shfl_xor(tm, 2));
        tm = fmaxf(tm, __shfl_xor(tm, 4));
        tm = fmaxf(tm, __shfl_xor(tm, 8));
        float mo = m_r[r];
        float mn = fmaxf(mo, tm);
        float alpha = exp2f((mo - mn) * L2E);
        m_r[r] = mn;
        float rs = 0.f;
#pragma unroll
        for (int nf = 0; nf < 8; ++nf) {
          float p = exp2f((s[nf][r] - mn) * L2E);
          s[nf][r] = p;
          rs += p;
        }
        rs += __shfl_xor(rs, 1);
        rs += __shfl_xor(rs, 2);
        rs += __shfl_xor(rs, 4);
        rs += __shfl_xor(rs, 8);
        l_r[r] = l_r[r] * alpha + rs;
#pragma unroll
        for (int nf = 0; nf < 8; ++nf) o[nf][r] *= alpha;
      }

#pragma unroll
      for (int nf = 0; nf < 8; ++nf)
#pragma unroll
        for (int r = 0; r < 4; ++r) {
          int rl = lgrp * 4 + r;
          int chunk = 2 * nf + (lane16 >> 3);
          int byte = rl * 256 + (((chunk ^ (rl & 7))) << 4) + ((lane16 & 7) << 1);
          *(bf16*)((char*)&Psm[w][0] + byte) = (bf16)s[nf][r];
        }
      bf16x8 pa[4];
#pragma unroll
      for (int kk = 0; kk < 4; ++kk) {
        int chunk = kk * 4 + lgrp;
        int byte = lane16 * 256 + (((chunk ^ (lane16 & 7))) << 4);
        pa[kk] = *(const bf16x8*)((char*)&Psm[w][0] + byte);
      }

#pragma unroll
      for (int nf = 0; nf < 8; ++nf) {
#pragma unroll
        for (int kk = 0; kk < 4; ++kk) {
          int hd = nf * 16 + lane16;
          int chunk = kk * 4 + lgrp;
          int byte = hd * 256 + (((chunk ^ (hd & 7))) << 4);
          bf16x8 vf = *(const bf16x8*)((char*)Vsm + byte);
          o[nf] = __builtin_amdgcn_mfma_f32_16x16x32_bf16(
              pa[kk], vf, o[nf], 0, 0, 0);
        }
      }

      __syncthreads();
    }

#pragma unroll
    for (int r = 0; r < 4; ++r) {
      float inv = 1.0f / l_r[r];
      int row = q0 + w * 16 + lgrp * 4 + r;
#pragma unroll
      for (int nf = 0; nf < 8; ++nf) {
        int hd = nf * 16 + lane16;
        Y[(size_t)(b * TT + row) * DM + h * HDD + hd] = (bf16)(o[nf][r] * inv);
      }
    }
  }
}

// ---------------------------------------------------------------- launch
extern "C" void kernel_launch(void* const* d_in, const int* in_sizes, int n_in,
                              void* d_out, int out_size, void* d_ws, size_t ws_size,
                              hipStream_t stream) {
  const float* x = (const float*)d_in[0];
  const float* Wqkv = (const float*)d_in[2];
  const float* bqkv = (const float*)d_in[3];
  const float* Wproj = (const float*)d_in[4];
  const float* bproj = (const float*)d_in[5];
  float* out = (float*)d_out;

  char* ws = (char*)d_ws;
  bf16* xb = (bf16*)ws;                 ws += (size_t)MM * DM * 2;
  bf16* Wqkvt = (bf16*)ws;              ws += (size_t)NQKV * DM * 2;
  bf16* Wprojt = (bf16*)ws;             ws += (size_t)DM * DM * 2;
  bf16* kb = (bf16*)ws;                 ws += (size_t)MM * DM * 2;
  bf16* vb = (bf16*)ws;                 ws += (size_t)MM * DM * 2;
  float* cosT = (float*)ws;             ws += (size_t)TT * 64 * 4;
  float* sinT = (float*)ws;             ws += (size_t)TT * 64 * 4;
  bf16* qb = (bf16*)d_out;              // q lives in d_out (overwritten by proj)
  bf16* yb = xb;                        // xb dead after QKV GEMM

  rope_table_k<<<dim3(512), dim3(256), 0, stream>>>(cosT, sinT);
  convert_x_k<<<dim3(4096), dim3(256), 0, stream>>>(x, xb);
  transpose_w_k<<<dim3(96, 32), dim3(256), 0, stream>>>(Wqkv, Wqkvt, DM, NQKV);
  transpose_w_k<<<dim3(32, 32), dim3(256), 0, stream>>>(Wproj, Wprojt, DM, DM);

  gemm8_qkv_k<<<dim3(16, 32), dim3(512), 0, stream>>>(
      xb, Wqkvt, bqkv, qb, kb, vb, MM, NQKV, DM);

  rope_apply_k<<<dim3(4096), dim3(256), 0, stream>>>(qb, cosT, sinT);
  rope_apply_k<<<dim3(4096), dim3(256), 0, stream>>>(kb, cosT, sinT);

  attn_k<<<dim3(8, 32), dim3(512), 0, stream>>>(qb, kb, vb, yb);

  gemm_bt_k<1><<<dim3(32, 16), dim3(256), 0, stream>>>(
      yb, Wprojt, bproj, nullptr, nullptr, nullptr, out, MM, DM, DM);
}

// Round 9
// 297.669 us; speedup vs baseline: 2.1225x; 1.0207x over previous
//
#include <hip/hip_runtime.h>
#include <hip/hip_bf16.h>
#include <stdint.h>
#include <stddef.h>

typedef __bf16 bf16;
typedef __attribute__((ext_vector_type(8))) __bf16 bf16x8;
typedef __attribute__((ext_vector_type(4))) __bf16 bf16x4;
typedef __attribute__((ext_vector_type(4))) float f32x4;

#define DM 2048      // model dim
#define NH 16        // heads
#define HDD 128      // head dim
#define BB 2         // batch
#define TT 2048      // seq len
#define MM (BB*TT)   // 4096 rows
#define NQKV (3*DM)  // 6144

#define L2E 1.4426950408889634f
#define ATT_SCALE 0.08838834764831845f   // 1/sqrt(128)
#define NEG_INF (-__builtin_inff())

static_assert(sizeof(bf16x8) == 16, "bf16x8 must be 16B");

#define SB0() __builtin_amdgcn_sched_barrier(0)
#define WAITV0() { asm volatile("s_waitcnt vmcnt(0)" ::: "memory"); SB0(); }
#define WAITL0() { asm volatile("s_waitcnt lgkmcnt(0)" ::: "memory"); SB0(); }
#define BARRIER8() { SB0(); __builtin_amdgcn_s_barrier(); SB0(); }

// ---------------------------------------------------------------- helpers
static __device__ __forceinline__ void gload_lds16(const void* g, void* l) {
  __builtin_amdgcn_global_load_lds(
      (__attribute__((address_space(1))) void*)g,
      (__attribute__((address_space(3))) void*)l, 16, 0, 0);
}

// ---------------------------------------------------------------- pre-pass
__global__ __launch_bounds__(256) void rope_table_k(float* __restrict__ cT,
                                                    float* __restrict__ sT) {
  int id = blockIdx.x * 256 + threadIdx.x;          // < 2048*64
  int t = id >> 6, i = id & 63;
  float freq = powf(10000.0f, -(float)i * (1.0f / 64.0f));
  float theta = (float)t * freq;
  float s, c;
  __sincosf(theta, &s, &c);
  cT[id] = c;
  sT[id] = s;
}

__global__ __launch_bounds__(256) void convert_x_k(const float* __restrict__ x,
                                                   bf16* __restrict__ xb) {
  size_t id = (size_t)blockIdx.x * 256 + threadIdx.x;
  size_t o = id * 8;
  float4 a = *(const float4*)(x + o);
  float4 b = *(const float4*)(x + o + 4);
  bf16x8 r;
  r[0] = (bf16)a.x; r[1] = (bf16)a.y; r[2] = (bf16)a.z; r[3] = (bf16)a.w;
  r[4] = (bf16)b.x; r[5] = (bf16)b.y; r[6] = (bf16)b.z; r[7] = (bf16)b.w;
  *(bf16x8*)(xb + o) = r;
}

// W (K x N) f32 -> Wt (N x K) bf16, 64x64 tiles
__global__ __launch_bounds__(256) void transpose_w_k(const float* __restrict__ W,
                                                     bf16* __restrict__ Wt,
                                                     int K, int N) {
  __shared__ float tile[64][65];
  int n0 = blockIdx.x * 64, k0 = blockIdx.y * 64;
  int t = threadIdx.x;
#pragma unroll
  for (int i = 0; i < 16; ++i) {
    int idx = t + i * 256;
    int r = idx >> 6, c = idx & 63;
    tile[r][c] = W[(size_t)(k0 + r) * N + n0 + c];
  }
  __syncthreads();
#pragma unroll
  for (int i = 0; i < 16; ++i) {
    int idx = t + i * 256;
    int r = idx >> 6, c = idx & 63;
    Wt[(size_t)(n0 + r) * K + k0 + c] = (bf16)tile[c][r];
  }
}

// in-place RoPE on (b,h,t,hd) bf16 buffer; half-split style
__global__ __launch_bounds__(256) void rope_apply_k(bf16* __restrict__ buf,
                                                    const float* __restrict__ cT,
                                                    const float* __restrict__ sT) {
  int id = blockIdx.x * 256 + threadIdx.x;   // < 32*2048*16
  int i4 = id & 15;
  int t = (id >> 4) & 2047;
  int bh = id >> 15;
  int idx0 = i4 * 4;
  size_t base = ((size_t)bh * TT + t) * HDD;
  bf16x4 x1 = *(const bf16x4*)(buf + base + idx0);
  bf16x4 x2 = *(const bf16x4*)(buf + base + 64 + idx0);
  float4 ct = *(const float4*)(cT + t * 64 + idx0);
  float4 st = *(const float4*)(sT + t * 64 + idx0);
  bf16x4 o1, o2;
  float c0, s0, a, b2;
#pragma unroll
  for (int j = 0; j < 4; ++j) {
    c0 = (j == 0) ? ct.x : (j == 1) ? ct.y : (j == 2) ? ct.z : ct.w;
    s0 = (j == 0) ? st.x : (j == 1) ? st.y : (j == 2) ? st.z : st.w;
    a = (float)x1[j];
    b2 = (float)x2[j];
    o1[j] = (bf16)(a * c0 - b2 * s0);
    o2[j] = (bf16)(a * s0 + b2 * c0);
  }
  *(bf16x4*)(buf + base + idx0) = o1;
  *(bf16x4*)(buf + base + 64 + idx0) = o2;
}

// ---------------------------------------------------------------- GEMM (proj)
// C(M,N) = A(M,K) * Bt(N,K)^T + bias.  128x128 tile, BK=64, 4 waves 2x2.
template <int EPI>
__global__ __launch_bounds__(256, 2) void gemm_bt_k(
    const bf16* __restrict__ A, const bf16* __restrict__ Bt,
    const float* __restrict__ bias,
    bf16* __restrict__ q_out, bf16* __restrict__ k_out, bf16* __restrict__ v_out,
    float* __restrict__ c_out, int M, int N, int K) {
  __shared__ __align__(16) bf16 Asm[128 * 64];
  __shared__ __align__(16) bf16 Bsm[128 * 64];
  const int tid = threadIdx.x;
  const int w = tid >> 6, l = tid & 63;
  const int lane16 = l & 15, lgrp = l >> 4;
  const int wm = w >> 1, wn = w & 1;

  int flat = blockIdx.y * gridDim.x + blockIdx.x;
  {
    const int nwg = gridDim.x * gridDim.y;
    const int cpx = nwg >> 3;
    flat = (flat & 7) * cpx + (flat >> 3);
  }
  const int bm = flat % gridDim.x;
  const int bn = flat / gridDim.x;

  const int l8r = l >> 3, l8c = l & 7;

  f32x4 acc[4][4] = {};

  for (int k0 = 0; k0 < K; k0 += 64) {
    __syncthreads();
#pragma unroll
    for (int i = 0; i < 4; ++i) {
      int slot = w * 4 + i;
      int row = slot * 8 + l8r;
      gload_lds16(A + (size_t)(bm * 128 + row) * K + k0 + l8c * 8,
                  &Asm[slot * 512]);
      gload_lds16(Bt + (size_t)(bn * 128 + row) * K + k0 + l8c * 8,
                  &Bsm[slot * 512]);
    }
    __syncthreads();
#pragma unroll
    for (int kk = 0; kk < 2; ++kk) {
      bf16x8 af[4], bfr[4];
#pragma unroll
      for (int mf = 0; mf < 4; ++mf) {
        int row = wm * 64 + mf * 16 + lane16;
        af[mf] = *(const bf16x8*)&Asm[row * 64 + kk * 32 + lgrp * 8];
      }
#pragma unroll
      for (int nf = 0; nf < 4; ++nf) {
        int col = wn * 64 + nf * 16 + lane16;
        bfr[nf] = *(const bf16x8*)&Bsm[col * 64 + kk * 32 + lgrp * 8];
      }
#pragma unroll
      for (int mf = 0; mf < 4; ++mf)
#pragma unroll
        for (int nf = 0; nf < 4; ++nf)
          acc[mf][nf] = __builtin_amdgcn_mfma_f32_16x16x32_bf16(
              af[mf], bfr[nf], acc[mf][nf], 0, 0, 0);
    }
  }

  if (EPI == 0) {
    const int which = bn >> 4;
    const int head = bn & 15;
    bf16* outb = (which == 0) ? q_out : (which == 1 ? k_out : v_out);
#pragma unroll
    for (int nf = 0; nf < 4; ++nf) {
      int hd = wn * 64 + nf * 16 + lane16;
      float bv = bias[bn * 128 + hd];
#pragma unroll
      for (int mf = 0; mf < 4; ++mf)
#pragma unroll
        for (int r = 0; r < 4; ++r) {
          int row = bm * 128 + wm * 64 + mf * 16 + lgrp * 4 + r;
          int b = row >> 11, t = row & 2047;
          outb[((size_t)(b * NH + head) * TT + t) * HDD + hd] =
              (bf16)(acc[mf][nf][r] + bv);
        }
    }
  } else {
#pragma unroll
    for (int nf = 0; nf < 4; ++nf) {
      int colg = bn * 128 + wn * 64 + nf * 16 + lane16;
      float bv = bias[colg];
#pragma unroll
      for (int mf = 0; mf < 4; ++mf)
#pragma unroll
        for (int r = 0; r < 4; ++r) {
          int row = bm * 128 + wm * 64 + mf * 16 + lgrp * 4 + r;
          c_out[(size_t)row * N + colg] = acc[mf][nf][r] + bv;
        }
    }
  }
}

// ---------------------------------------------------------------- GEMM (QKV, 4-phase 256x192)
#define MFMA_Q(MF0, NF0, NCNT)                                             \
  do {                                                                     \
    __builtin_amdgcn_s_setprio(1);                                         \
    _Pragma("unroll") for (int mf = 0; mf < 4; ++mf)                       \
    _Pragma("unroll") for (int nf = 0; nf < (NCNT); ++nf)                  \
    _Pragma("unroll") for (int kk = 0; kk < 2; ++kk)                       \
      acc[(MF0) + mf][(NF0) + nf] = __builtin_amdgcn_mfma_f32_16x16x32_bf16( \
          af[(MF0) + mf][kk], bfr[(NF0) + nf][kk], acc[(MF0) + mf][(NF0) + nf], 0, 0, 0); \
    __builtin_amdgcn_s_setprio(0);                                         \
  } while (0)

__global__ __launch_bounds__(512, 2) void gemm8_qkv_k(
    const bf16* __restrict__ A, const bf16* __restrict__ Bt,
    const float* __restrict__ bias,
    bf16* __restrict__ q_out, bf16* __restrict__ k_out, bf16* __restrict__ v_out,
    int M, int N, int K) {
  __shared__ __align__(16) char Lsm[2][57344];   // [buf][A:32KB | B:24KB]
  const int tid = threadIdx.x;
  const int wid = tid >> 6, l = tid & 63;
  const int lane16 = l & 15, lgrp = l >> 4;
  const int wm = wid >> 2, wn = wid & 3;

  int flat = blockIdx.y * gridDim.x + blockIdx.x;
  {
    const int cpx = (gridDim.x * gridDim.y) >> 3;
    flat = (flat & 7) * cpx + (flat >> 3);
  }
  const int bm = flat % gridDim.x;       // 0..15  (M/256)
  const int bn = flat / gridDim.x;       // 0..31  (N/192)
  const int NT = K >> 6;

  const int schunk = (l & 7) ^ ((l >> 3) & 7);
  const bf16* gA = A + (size_t)(bm * 256 + wid * 8 + (l >> 3)) * K + schunk * 8;
  const bf16* gB = Bt + (size_t)(bn * 192 + wid * 8 + (l >> 3)) * K + schunk * 8;

  auto stage_unit = [&](int mat, int t, int u, int buf) {
    const bf16* g = (mat ? gB : gA) + (size_t)(u * 64) * K + t * 64;
    gload_lds16(g, &Lsm[buf][(mat ? 32768 : 0) + u * 8192 + wid * 1024]);
  };

  f32x4 acc[8][3] = {};

#pragma unroll
  for (int u = 0; u < 4; ++u) stage_unit(0, 0, u, 0);
#pragma unroll
  for (int u = 0; u < 3; ++u) stage_unit(1, 0, u, 0);

  for (int t = 0; t < NT; ++t) {
    const int cur = t & 1;
    const char* As = &Lsm[cur][0];
    const char* Bs = &Lsm[cur][32768];
    bf16x8 af[8][2], bfr[3][2];

    WAITV0();
    BARRIER8();

    // ---- phase 0
#pragma unroll
    for (int mf = 0; mf < 4; ++mf)
#pragma unroll
      for (int kk = 0; kk < 2; ++kk) {
        int row = wm * 128 + mf * 16 + lane16;
        int ch = (kk * 4 + lgrp) ^ (lane16 & 7);
        af[mf][kk] = *(const bf16x8*)(As + row * 128 + ch * 16);
      }
#pragma unroll
    for (int nf = 0; nf < 2; ++nf)
#pragma unroll
      for (int kk = 0; kk < 2; ++kk) {
        int row = wn * 48 + nf * 16 + lane16;
        int ch = (kk * 4 + lgrp) ^ (lane16 & 7);
        bfr[nf][kk] = *(const bf16x8*)(Bs + row * 128 + ch * 16);
      }
    if (t + 1 < NT) {
#pragma unroll
      for (int u = 0; u < 4; ++u) stage_unit(0, t + 1, u, cur ^ 1);
    }
    WAITL0();
    MFMA_Q(0, 0, 2);
    BARRIER8();

    // ---- phase 1
#pragma unroll
    for (int mf = 4; mf < 8; ++mf)
#pragma unroll
      for (int kk = 0; kk < 2; ++kk) {
        int row = wm * 128 + mf * 16 + lane16;
        int ch = (kk * 4 + lgrp) ^ (lane16 & 7);
        af[mf][kk] = *(const bf16x8*)(As + row * 128 + ch * 16);
      }
#pragma unroll
    for (int kk = 0; kk < 2; ++kk) {
      int row = wn * 48 + 32 + lane16;
      int ch = (kk * 4 + lgrp) ^ (lane16 & 7);
      bfr[2][kk] = *(const bf16x8*)(Bs + row * 128 + ch * 16);
    }
    if (t + 1 < NT) {
#pragma unroll
      for (int u = 0; u < 3; ++u) stage_unit(1, t + 1, u, cur ^ 1);
    }
    WAITL0();
    MFMA_Q(0, 2, 1);
    BARRIER8();

    // ---- phase 2
    MFMA_Q(4, 0, 2);
    BARRIER8();

    // ---- phase 3
    MFMA_Q(4, 2, 1);
  }

  // ---- epilogue
#pragma unroll
  for (int nf = 0; nf < 3; ++nf) {
    int colg = bn * 192 + wn * 48 + nf * 16 + lane16;
    int which = colg >> 11;
    bf16* outb = (which == 0) ? q_out : (which == 1 ? k_out : v_out);
    int head = (colg >> 7) & 15, hd = colg & 127;
    float bv = bias[colg];
#pragma unroll
    for (int mf = 0; mf < 8; ++mf)
#pragma unroll
      for (int r = 0; r < 4; ++r) {
        int row = bm * 256 + wm * 128 + mf * 16 + lgrp * 4 + r;
        int bb = row >> 11, tt2 = row & 2047;
        outb[((size_t)(bb * NH + head) * TT + tt2) * HDD + hd] =
            (bf16)(acc[mf][nf][r] + bv);
      }
  }
}

// ---------------------------------------------------------------- attention
// grid (8, B*H) = 256 blocks, 8 waves (512 thr); q-tiles {bx, 15-bx} (128 rows),
// 17 K-tiles of 128 keys per block, 1 block/CU.
// Pipeline = R7-proven (__syncthreads-fenced, single K buffer). ONLY change
// from the 126us version: 4-bit swizzle g4(row) = (row ^ (row>>3)) & 15 on
// K/V/P (was 3-bit row&7) -> conflict-free b128 reads, write_V 16->4-way.
__global__ __launch_bounds__(512, 2) void attn_k(
    const bf16* __restrict__ Q, const bf16* __restrict__ Kt,
    const bf16* __restrict__ V, bf16* __restrict__ Y) {
  __shared__ __align__(16) bf16 Ksm[128 * 128];   // [key][hd], chunk^=g4(key), 32KB
  __shared__ __align__(16) bf16 Vsm[128 * 128];   // [hd][key], chunk^=g4(hd), 32KB
  __shared__ __align__(16) bf16 Psm[8][16 * 128]; // per-wave P, chunk^=g4(row), 32KB
  const int tid = threadIdx.x, w = tid >> 6, l = tid & 63;
  const int lane16 = l & 15, lgrp = l >> 4;
  const int bh = blockIdx.y;
  const int b = bh >> 4, h = bh & 15;
  const size_t base = (size_t)bh * TT * HDD;

  uint4 vreg[4];
  const int vg = tid >> 4, vh8 = tid & 15;

  auto load_V = [&](int k0) {
#pragma unroll
    for (int kq = 0; kq < 4; ++kq)
      vreg[kq] = *(const uint4*)(V + base + (size_t)(k0 + vg * 4 + kq) * HDD + vh8 * 8);
  };
  auto issue_K = [&](int k0) {
#pragma unroll
    for (int i = 0; i < 4; ++i) {
      int key = w * 16 + i * 4 + (l >> 4);
      int c = (l & 15) ^ ((key ^ (key >> 3)) & 15);
      gload_lds16(Kt + base + (size_t)(k0 + key) * HDD + c * 8,
                  &Ksm[(w * 16 + i * 4) * 128 + (l & 15) * 8]);
    }
  };
  auto write_V = [&]() {
    const unsigned* dw = (const unsigned*)vreg;
    int hd0 = vh8 * 8;
#pragma unroll
    for (int j = 0; j < 8; ++j) {
      int ww = j >> 1;
      unsigned sel = (j & 1) ? 0x07060302u : 0x05040100u;
      uint2 val;
      val.x = __builtin_amdgcn_perm(dw[4 + ww], dw[0 + ww], sel);
      val.y = __builtin_amdgcn_perm(dw[12 + ww], dw[8 + ww], sel);
      int hd = hd0 + j;
      int ch = (vg >> 1) ^ ((hd ^ (hd >> 3)) & 15);
      *(uint2*)((char*)Vsm + hd * 256 + (ch << 4) + ((vg & 1) << 3)) = val;
    }
  };

  for (int pass = 0; pass < 2; ++pass) {
    const int qt = (pass == 0) ? (int)blockIdx.x : 15 - (int)blockIdx.x;
    const int q0 = qt * 128;
    const int nt = qt + 1;

    bf16x8 qa[4];
    {
      int row = q0 + w * 16 + lane16;
#pragma unroll
      for (int kk = 0; kk < 4; ++kk)
        qa[kk] = *(const bf16x8*)(Q + base + (size_t)row * HDD + kk * 32 + lgrp * 8);
    }

    f32x4 o[8] = {};
    float m_r[4], l_r[4];
#pragma unroll
    for (int r = 0; r < 4; ++r) { m_r[r] = NEG_INF; l_r[r] = 0.f; }

    for (int kt = 0; kt < nt; ++kt) {
      const int k0 = kt * 128;
      load_V(k0);           // V loads first (oldest in vmcnt queue)
      issue_K(k0);          // K direct-to-LDS, in flight during V repack
      write_V();            // waits only the 4 V loads; WAR safe (prev barrier)
      __syncthreads();      // drains vmcnt+lgkmcnt: K & V staged for all waves

      // ---- S = Q K^T
      f32x4 s[8] = {};
#pragma unroll
      for (int kk = 0; kk < 4; ++kk) {
#pragma unroll
        for (int nf = 0; nf < 8; ++nf) {
          int key = nf * 16 + lane16;
          int ch = (kk * 4 + lgrp) ^ ((key ^ (key >> 3)) & 15);
          bf16x8 kf = *(const bf16x8*)((char*)Ksm + key * 256 + (ch << 4));
          s[nf] = __builtin_amdgcn_mfma_f32_16x16x32_bf16(
              qa[kk], kf, s[nf], 0, 0, 0);
        }
      }

      // ---- scale + causal mask
      const int rowbase = q0 + w * 16 + lgrp * 4;
      const bool needmask = (k0 + 127 > q0 + w * 16);
#pragma unroll
      for (int nf = 0; nf < 8; ++nf) {
        int col = k0 + nf * 16 + lane16;
#pragma unroll
        for (int r = 0; r < 4; ++r) {
          float sv = s[nf][r] * ATT_SCALE;
          if (needmask && col > rowbase + r) sv = -3.0e38f;
          s[nf][r] = sv;
        }
      }

      // ---- online softmax
#pragma unroll
      for (int r = 0; r < 4; ++r) {
        float tm = fmaxf(fmaxf(fmaxf(s[0][r], s[1][r]), fmaxf(s[2][r], s[3][r])),
                         fmaxf(fmaxf(s[4][r], s[5][r]), fmaxf(s[6][r], s[7][r])));
        tm = fmaxf(tm, __shfl_xor(tm, 1));
        tm = fmaxf(tm, __shfl_xor(tm, 2));
        tm = fmaxf(tm, __shfl_xor(tm, 4));
        tm = fmaxf(tm, __shfl_xor(tm, 8));
        float mo = m_r[r];
        float mn = fmaxf(mo, tm);
        float alpha = exp2f((mo - mn) * L2E);
        m_r[r] = mn;
        float rs = 0.f;
#pragma unroll
        for (int nf = 0; nf < 8; ++nf) {
          float p = exp2f((s[nf][r] - mn) * L2E);
          s[nf][r] = p;
          rs += p;
        }
        rs += __shfl_xor(rs, 1);
        rs += __shfl_xor(rs, 2);
        rs += __shfl_xor(rs, 4);
        rs += __shfl_xor(rs, 8);
        l_r[r] = l_r[r] * alpha + rs;
#pragma unroll
        for (int nf = 0; nf < 8; ++nf) o[nf][r] *= alpha;
      }

      // ---- P -> LDS (per-wave region, same-wave readback; no barrier)
#pragma unroll
      for (int nf = 0; nf < 8; ++nf)
#pragma unroll
        for (int r = 0; r < 4; ++r) {
          int rl = lgrp * 4 + r;
          int ch = (2 * nf + (lane16 >> 3)) ^ ((rl ^ (rl >> 3)) & 15);
          int byte = rl * 256 + (ch << 4) + ((lane16 & 7) << 1);
          *(bf16*)((char*)&Psm[w][0] + byte) = (bf16)s[nf][r];
        }
      bf16x8 pa[4];
#pragma unroll
      for (int kk = 0; kk < 4; ++kk) {
        int ch = (kk * 4 + lgrp) ^ ((lane16 ^ (lane16 >> 3)) & 15);
        pa[kk] = *(const bf16x8*)((char*)&Psm[w][0] + lane16 * 256 + (ch << 4));
      }

      // ---- O += P V
#pragma unroll
      for (int nf = 0; nf < 8; ++nf) {
#pragma unroll
        for (int kk = 0; kk < 4; ++kk) {
          int hd = nf * 16 + lane16;
          int ch = (kk * 4 + lgrp) ^ ((hd ^ (hd >> 3)) & 15);
          bf16x8 vf = *(const bf16x8*)((char*)Vsm + hd * 256 + (ch << 4));
          o[nf] = __builtin_amdgcn_mfma_f32_16x16x32_bf16(
              pa[kk], vf, o[nf], 0, 0, 0);
        }
      }

      __syncthreads();      // all waves done reading Ksm/Vsm before next stage
    }

    // ---- finalize: O / l -> Y (b,t,D) bf16
#pragma unroll
    for (int r = 0; r < 4; ++r) {
      float inv = 1.0f / l_r[r];
      int row = q0 + w * 16 + lgrp * 4 + r;
#pragma unroll
      for (int nf = 0; nf < 8; ++nf) {
        int hd = nf * 16 + lane16;
        Y[(size_t)(b * TT + row) * DM + h * HDD + hd] = (bf16)(o[nf][r] * inv);
      }
    }
  }
}

// ---------------------------------------------------------------- launch
extern "C" void kernel_launch(void* const* d_in, const int* in_sizes, int n_in,
                              void* d_out, int out_size, void* d_ws, size_t ws_size,
                              hipStream_t stream) {
  const float* x = (const float*)d_in[0];
  const float* Wqkv = (const float*)d_in[2];
  const float* bqkv = (const float*)d_in[3];
  const float* Wproj = (const float*)d_in[4];
  const float* bproj = (const float*)d_in[5];
  float* out = (float*)d_out;

  char* ws = (char*)d_ws;
  bf16* xb = (bf16*)ws;                 ws += (size_t)MM * DM * 2;
  bf16* Wqkvt = (bf16*)ws;              ws += (size_t)NQKV * DM * 2;
  bf16* Wprojt = (bf16*)ws;             ws += (size_t)DM * DM * 2;
  bf16* kb = (bf16*)ws;                 ws += (size_t)MM * DM * 2;
  bf16* vb = (bf16*)ws;                 ws += (size_t)MM * DM * 2;
  float* cosT = (float*)ws;             ws += (size_t)TT * 64 * 4;
  float* sinT = (float*)ws;             ws += (size_t)TT * 64 * 4;
  bf16* qb = (bf16*)d_out;              // q lives in d_out (overwritten by proj)
  bf16* yb = xb;                        // xb dead after QKV GEMM

  rope_table_k<<<dim3(512), dim3(256), 0, stream>>>(cosT, sinT);
  convert_x_k<<<dim3(4096), dim3(256), 0, stream>>>(x, xb);
  transpose_w_k<<<dim3(96, 32), dim3(256), 0, stream>>>(Wqkv, Wqkvt, DM, NQKV);
  transpose_w_k<<<dim3(32, 32), dim3(256), 0, stream>>>(Wproj, Wprojt, DM, DM);

  gemm8_qkv_k<<<dim3(16, 32), dim3(512), 0, stream>>>(
      xb, Wqkvt, bqkv, qb, kb, vb, MM, NQKV, DM);

  rope_apply_k<<<dim3(4096), dim3(256), 0, stream>>>(qb, cosT, sinT);
  rope_apply_k<<<dim3(4096), dim3(256), 0, stream>>>(kb, cosT, sinT);

  attn_k<<<dim3(8, 32), dim3(512), 0, stream>>>(qb, kb, vb, yb);

  gemm_bt_k<1><<<dim3(32, 16), dim3(256), 0, stream>>>(
      yb, Wprojt, bproj, nullptr, nullptr, nullptr, out, MM, DM, DM);
}

// Round 11
// 285.736 us; speedup vs baseline: 2.2112x; 1.0418x over previous
//
#include <hip/hip_runtime.h>
#include <hip/hip_bf16.h>
#include <stdint.h>
#include <stddef.h>

typedef __bf16 bf16;
typedef __attribute__((ext_vector_type(8))) __bf16 bf16x8;
typedef __attribute__((ext_vector_type(4))) __bf16 bf16x4;
typedef __attribute__((ext_vector_type(4))) float f32x4;

#define DM 2048      // model dim
#define NH 16        // heads
#define HDD 128      // head dim
#define BB 2         // batch
#define TT 2048      // seq len
#define MM (BB*TT)   // 4096 rows
#define NQKV (3*DM)  // 6144

#define L2E 1.4426950408889634f
#define ATT_SCALE 0.08838834764831845f   // 1/sqrt(128)
#define NEG_INF (-__builtin_inff())

static_assert(sizeof(bf16x8) == 16, "bf16x8 must be 16B");

#define SB0() __builtin_amdgcn_sched_barrier(0)
#define WAITV0() { asm volatile("s_waitcnt vmcnt(0)" ::: "memory"); SB0(); }
#define WAITL0() { asm volatile("s_waitcnt lgkmcnt(0)" ::: "memory"); SB0(); }
#define BARRIER8() { SB0(); __builtin_amdgcn_s_barrier(); SB0(); }

// ---------------------------------------------------------------- helpers
static __device__ __forceinline__ void gload_lds16(const void* g, void* l) {
  __builtin_amdgcn_global_load_lds(
      (__attribute__((address_space(1))) void*)g,
      (__attribute__((address_space(3))) void*)l, 16, 0, 0);
}

// ---------------------------------------------------------------- pre-pass
__global__ __launch_bounds__(256) void rope_table_k(float* __restrict__ cT,
                                                    float* __restrict__ sT) {
  int id = blockIdx.x * 256 + threadIdx.x;          // < 2048*64
  int t = id >> 6, i = id & 63;
  float freq = powf(10000.0f, -(float)i * (1.0f / 64.0f));
  float theta = (float)t * freq;
  float s, c;
  __sincosf(theta, &s, &c);
  cT[id] = c;
  sT[id] = s;
}

__global__ __launch_bounds__(256) void convert_x_k(const float* __restrict__ x,
                                                   bf16* __restrict__ xb) {
  size_t id = (size_t)blockIdx.x * 256 + threadIdx.x;
  size_t o = id * 8;
  float4 a = *(const float4*)(x + o);
  float4 b = *(const float4*)(x + o + 4);
  bf16x8 r;
  r[0] = (bf16)a.x; r[1] = (bf16)a.y; r[2] = (bf16)a.z; r[3] = (bf16)a.w;
  r[4] = (bf16)b.x; r[5] = (bf16)b.y; r[6] = (bf16)b.z; r[7] = (bf16)b.w;
  *(bf16x8*)(xb + o) = r;
}

// W (K x N) f32 -> Wt (N x K) bf16, 64x64 tiles
__global__ __launch_bounds__(256) void transpose_w_k(const float* __restrict__ W,
                                                     bf16* __restrict__ Wt,
                                                     int K, int N) {
  __shared__ float tile[64][65];
  int n0 = blockIdx.x * 64, k0 = blockIdx.y * 64;
  int t = threadIdx.x;
#pragma unroll
  for (int i = 0; i < 16; ++i) {
    int idx = t + i * 256;
    int r = idx >> 6, c = idx & 63;
    tile[r][c] = W[(size_t)(k0 + r) * N + n0 + c];
  }
  __syncthreads();
#pragma unroll
  for (int i = 0; i < 16; ++i) {
    int idx = t + i * 256;
    int r = idx >> 6, c = idx & 63;
    Wt[(size_t)(n0 + r) * K + k0 + c] = (bf16)tile[c][r];
  }
}

// in-place RoPE on (b,h,t,hd) bf16 buffer; half-split style
__global__ __launch_bounds__(256) void rope_apply_k(bf16* __restrict__ buf,
                                                    const float* __restrict__ cT,
                                                    const float* __restrict__ sT) {
  int id = blockIdx.x * 256 + threadIdx.x;   // < 32*2048*16
  int i4 = id & 15;
  int t = (id >> 4) & 2047;
  int bh = id >> 15;
  int idx0 = i4 * 4;
  size_t base = ((size_t)bh * TT + t) * HDD;
  bf16x4 x1 = *(const bf16x4*)(buf + base + idx0);
  bf16x4 x2 = *(const bf16x4*)(buf + base + 64 + idx0);
  float4 ct = *(const float4*)(cT + t * 64 + idx0);
  float4 st = *(const float4*)(sT + t * 64 + idx0);
  bf16x4 o1, o2;
  float c0, s0, a, b2;
#pragma unroll
  for (int j = 0; j < 4; ++j) {
    c0 = (j == 0) ? ct.x : (j == 1) ? ct.y : (j == 2) ? ct.z : ct.w;
    s0 = (j == 0) ? st.x : (j == 1) ? st.y : (j == 2) ? st.z : st.w;
    a = (float)x1[j];
    b2 = (float)x2[j];
    o1[j] = (bf16)(a * c0 - b2 * s0);
    o2[j] = (bf16)(a * s0 + b2 * c0);
  }
  *(bf16x4*)(buf + base + idx0) = o1;
  *(bf16x4*)(buf + base + 64 + idx0) = o2;
}

// ---------------------------------------------------------------- GEMM (QKV, 4-phase 256x192)
#define MFMA_Q(MF0, NF0, NCNT)                                             \
  do {                                                                     \
    __builtin_amdgcn_s_setprio(1);                                         \
    _Pragma("unroll") for (int mf = 0; mf < 4; ++mf)                       \
    _Pragma("unroll") for (int nf = 0; nf < (NCNT); ++nf)                  \
    _Pragma("unroll") for (int kk = 0; kk < 2; ++kk)                       \
      acc[(MF0) + mf][(NF0) + nf] = __builtin_amdgcn_mfma_f32_16x16x32_bf16( \
          af[(MF0) + mf][kk], bfr[(NF0) + nf][kk], acc[(MF0) + mf][(NF0) + nf], 0, 0, 0); \
    __builtin_amdgcn_s_setprio(0);                                         \
  } while (0)

__global__ __launch_bounds__(512, 2) void gemm8_qkv_k(
    const bf16* __restrict__ A, const bf16* __restrict__ Bt,
    const float* __restrict__ bias,
    bf16* __restrict__ q_out, bf16* __restrict__ k_out, bf16* __restrict__ v_out,
    int M, int N, int K) {
  __shared__ __align__(16) char Lsm[2][57344];   // [buf][A:32KB | B:24KB]
  const int tid = threadIdx.x;
  const int wid = tid >> 6, l = tid & 63;
  const int lane16 = l & 15, lgrp = l >> 4;
  const int wm = wid >> 2, wn = wid & 3;

  int flat = blockIdx.y * gridDim.x + blockIdx.x;
  {
    const int cpx = (gridDim.x * gridDim.y) >> 3;
    flat = (flat & 7) * cpx + (flat >> 3);
  }
  const int bm = flat % gridDim.x;       // 0..15  (M/256)
  const int bn = flat / gridDim.x;       // 0..31  (N/192)
  const int NT = K >> 6;

  const int schunk = (l & 7) ^ ((l >> 3) & 7);
  const bf16* gA = A + (size_t)(bm * 256 + wid * 8 + (l >> 3)) * K + schunk * 8;
  const bf16* gB = Bt + (size_t)(bn * 192 + wid * 8 + (l >> 3)) * K + schunk * 8;

  auto stage_unit = [&](int mat, int t, int u, int buf) {
    const bf16* g = (mat ? gB : gA) + (size_t)(u * 64) * K + t * 64;
    gload_lds16(g, &Lsm[buf][(mat ? 32768 : 0) + u * 8192 + wid * 1024]);
  };

  f32x4 acc[8][3] = {};

#pragma unroll
  for (int u = 0; u < 4; ++u) stage_unit(0, 0, u, 0);
#pragma unroll
  for (int u = 0; u < 3; ++u) stage_unit(1, 0, u, 0);

  for (int t = 0; t < NT; ++t) {
    const int cur = t & 1;
    const char* As = &Lsm[cur][0];
    const char* Bs = &Lsm[cur][32768];
    bf16x8 af[8][2], bfr[3][2];

    WAITV0();
    BARRIER8();

    // ---- phase 0
#pragma unroll
    for (int mf = 0; mf < 4; ++mf)
#pragma unroll
      for (int kk = 0; kk < 2; ++kk) {
        int row = wm * 128 + mf * 16 + lane16;
        int ch = (kk * 4 + lgrp) ^ (lane16 & 7);
        af[mf][kk] = *(const bf16x8*)(As + row * 128 + ch * 16);
      }
#pragma unroll
    for (int nf = 0; nf < 2; ++nf)
#pragma unroll
      for (int kk = 0; kk < 2; ++kk) {
        int row = wn * 48 + nf * 16 + lane16;
        int ch = (kk * 4 + lgrp) ^ (lane16 & 7);
        bfr[nf][kk] = *(const bf16x8*)(Bs + row * 128 + ch * 16);
      }
    if (t + 1 < NT) {
#pragma unroll
      for (int u = 0; u < 4; ++u) stage_unit(0, t + 1, u, cur ^ 1);
    }
    WAITL0();
    MFMA_Q(0, 0, 2);
    BARRIER8();

    // ---- phase 1
#pragma unroll
    for (int mf = 4; mf < 8; ++mf)
#pragma unroll
      for (int kk = 0; kk < 2; ++kk) {
        int row = wm * 128 + mf * 16 + lane16;
        int ch = (kk * 4 + lgrp) ^ (lane16 & 7);
        af[mf][kk] = *(const bf16x8*)(As + row * 128 + ch * 16);
      }
#pragma unroll
    for (int kk = 0; kk < 2; ++kk) {
      int row = wn * 48 + 32 + lane16;
      int ch = (kk * 4 + lgrp) ^ (lane16 & 7);
      bfr[2][kk] = *(const bf16x8*)(Bs + row * 128 + ch * 16);
    }
    if (t + 1 < NT) {
#pragma unroll
      for (int u = 0; u < 3; ++u) stage_unit(1, t + 1, u, cur ^ 1);
    }
    WAITL0();
    MFMA_Q(0, 2, 1);
    BARRIER8();

    // ---- phase 2
    MFMA_Q(4, 0, 2);
    BARRIER8();

    // ---- phase 3
    MFMA_Q(4, 2, 1);
  }

  // ---- epilogue
#pragma unroll
  for (int nf = 0; nf < 3; ++nf) {
    int colg = bn * 192 + wn * 48 + nf * 16 + lane16;
    int which = colg >> 11;
    bf16* outb = (which == 0) ? q_out : (which == 1 ? k_out : v_out);
    int head = (colg >> 7) & 15, hd = colg & 127;
    float bv = bias[colg];
#pragma unroll
    for (int mf = 0; mf < 8; ++mf)
#pragma unroll
      for (int r = 0; r < 4; ++r) {
        int row = bm * 256 + wm * 128 + mf * 16 + lgrp * 4 + r;
        int bb = row >> 11, tt2 = row & 2047;
        outb[((size_t)(bb * NH + head) * TT + tt2) * HDD + hd] =
            (bf16)(acc[mf][nf][r] + bv);
      }
  }
}

// ---------------------------------------------------------------- GEMM (proj, 4-phase 256x128)
// 512 thr = 8 waves (2M x 4N); per-wave output 128x32; BK=64; 96KB LDS dbuf.
// grid 16x16 = 256 blocks = exactly 1 round at 1 block/CU (zero tail).
// Same staging geometry / swizzle involution / barrier discipline as QKV.
__global__ __launch_bounds__(512, 2) void gemm4_proj_k(
    const bf16* __restrict__ A, const bf16* __restrict__ Bt,
    const float* __restrict__ bias, float* __restrict__ c_out,
    int M, int N, int K) {
  __shared__ __align__(16) char Lsm[2][49152];   // [buf][A:32KB | B:16KB]
  const int tid = threadIdx.x;
  const int wid = tid >> 6, l = tid & 63;
  const int lane16 = l & 15, lgrp = l >> 4;
  const int wm = wid >> 2, wn = wid & 3;

  int flat = blockIdx.y * gridDim.x + blockIdx.x;
  {
    const int cpx = (gridDim.x * gridDim.y) >> 3;
    flat = (flat & 7) * cpx + (flat >> 3);
  }
  const int bm = flat % gridDim.x;       // 0..15 (M/256)
  const int bn = flat / gridDim.x;       // 0..15 (N/128)
  const int NT = K >> 6;

  const int schunk = (l & 7) ^ ((l >> 3) & 7);
  const bf16* gA = A + (size_t)(bm * 256 + wid * 8 + (l >> 3)) * K + schunk * 8;
  const bf16* gB = Bt + (size_t)(bn * 128 + wid * 8 + (l >> 3)) * K + schunk * 8;

  auto stage_unit = [&](int mat, int t, int u, int buf) {
    const bf16* g = (mat ? gB : gA) + (size_t)(u * 64) * K + t * 64;
    gload_lds16(g, &Lsm[buf][(mat ? 32768 : 0) + u * 8192 + wid * 1024]);
  };

  f32x4 acc[8][2] = {};

  // prologue: tile 0 (A:4 units, B:2 units) -> buf0
#pragma unroll
  for (int u = 0; u < 4; ++u) stage_unit(0, 0, u, 0);
#pragma unroll
  for (int u = 0; u < 2; ++u) stage_unit(1, 0, u, 0);

  for (int t = 0; t < NT; ++t) {
    const int cur = t & 1;
    const char* As = &Lsm[cur][0];
    const char* Bs = &Lsm[cur][32768];
    bf16x8 af[8][2], bfr[2][2];

    WAITV0();
    BARRIER8();

    // ---- phase 0: read af[0..3] + all bfr; stage t+1 A; MFMA (0,0)
#pragma unroll
    for (int mf = 0; mf < 4; ++mf)
#pragma unroll
      for (int kk = 0; kk < 2; ++kk) {
        int row = wm * 128 + mf * 16 + lane16;
        int ch = (kk * 4 + lgrp) ^ (lane16 & 7);
        af[mf][kk] = *(const bf16x8*)(As + row * 128 + ch * 16);
      }
#pragma unroll
    for (int nf = 0; nf < 2; ++nf)
#pragma unroll
      for (int kk = 0; kk < 2; ++kk) {
        int row = wn * 32 + nf * 16 + lane16;
        int ch = (kk * 4 + lgrp) ^ (lane16 & 7);
        bfr[nf][kk] = *(const bf16x8*)(Bs + row * 128 + ch * 16);
      }
    if (t + 1 < NT) {
#pragma unroll
      for (int u = 0; u < 4; ++u) stage_unit(0, t + 1, u, cur ^ 1);
    }
    WAITL0();
    MFMA_Q(0, 0, 1);
    BARRIER8();

    // ---- phase 1: read af[4..7]; stage t+1 B; MFMA (0,1)
#pragma unroll
    for (int mf = 4; mf < 8; ++mf)
#pragma unroll
      for (int kk = 0; kk < 2; ++kk) {
        int row = wm * 128 + mf * 16 + lane16;
        int ch = (kk * 4 + lgrp) ^ (lane16 & 7);
        af[mf][kk] = *(const bf16x8*)(As + row * 128 + ch * 16);
      }
    if (t + 1 < NT) {
#pragma unroll
      for (int u = 0; u < 2; ++u) stage_unit(1, t + 1, u, cur ^ 1);
    }
    WAITL0();
    MFMA_Q(0, 1, 1);
    BARRIER8();

    // ---- phase 2
    MFMA_Q(4, 0, 1);
    BARRIER8();

    // ---- phase 3; loop-top WAITV0+BARRIER closes the tile
    MFMA_Q(4, 1, 1);
  }

  // ---- epilogue: bias + f32 row-major store
#pragma unroll
  for (int nf = 0; nf < 2; ++nf) {
    int colg = bn * 128 + wn * 32 + nf * 16 + lane16;
    float bv = bias[colg];
#pragma unroll
    for (int mf = 0; mf < 8; ++mf)
#pragma unroll
      for (int r = 0; r < 4; ++r) {
        int row = bm * 256 + wm * 128 + mf * 16 + lgrp * 4 + r;
        c_out[(size_t)row * N + colg] = acc[mf][nf][r] + bv;
      }
  }
}

// ---------------------------------------------------------------- attention
// R9-proven version (118.7us): grid (8, B*H) = 256 blocks, 8 waves (512 thr);
// q-tiles {bx, 15-bx} (128 rows), 17 K-tiles of 128 keys per block, 1 block/CU.
// 4-bit swizzle g4(row) = (row ^ (row>>3)) & 15 on K/V/P. Single K buffer,
// __syncthreads-fenced staging. NO cross-tile prefetch (retired: R8/R10 fails).
__global__ __launch_bounds__(512, 2) void attn_k(
    const bf16* __restrict__ Q, const bf16* __restrict__ Kt,
    const bf16* __restrict__ V, bf16* __restrict__ Y) {
  __shared__ __align__(16) bf16 Ksm[128 * 128];   // [key][hd], chunk^=g4(key), 32KB
  __shared__ __align__(16) bf16 Vsm[128 * 128];   // [hd][key], chunk^=g4(hd), 32KB
  __shared__ __align__(16) bf16 Psm[8][16 * 128]; // per-wave P, chunk^=g4(row), 32KB
  const int tid = threadIdx.x, w = tid >> 6, l = tid & 63;
  const int lane16 = l & 15, lgrp = l >> 4;
  const int bh = blockIdx.y;
  const int b = bh >> 4, h = bh & 15;
  const size_t base = (size_t)bh * TT * HDD;

  uint4 vreg[4];
  const int vg = tid >> 4, vh8 = tid & 15;

  auto load_V = [&](int k0) {
#pragma unroll
    for (int kq = 0; kq < 4; ++kq)
      vreg[kq] = *(const uint4*)(V + base + (size_t)(k0 + vg * 4 + kq) * HDD + vh8 * 8);
  };
  auto issue_K = [&](int k0) {
#pragma unroll
    for (int i = 0; i < 4; ++i) {
      int key = w * 16 + i * 4 + (l >> 4);
      int c = (l & 15) ^ ((key ^ (key >> 3)) & 15);
      gload_lds16(Kt + base + (size_t)(k0 + key) * HDD + c * 8,
                  &Ksm[(w * 16 + i * 4) * 128 + (l & 15) * 8]);
    }
  };
  auto write_V = [&]() {
    const unsigned* dw = (const unsigned*)vreg;
    int hd0 = vh8 * 8;
#pragma unroll
    for (int j = 0; j < 8; ++j) {
      int ww = j >> 1;
      unsigned sel = (j & 1) ? 0x07060302u : 0x05040100u;
      uint2 val;
      val.x = __builtin_amdgcn_perm(dw[4 + ww], dw[0 + ww], sel);
      val.y = __builtin_amdgcn_perm(dw[12 + ww], dw[8 + ww], sel);
      int hd = hd0 + j;
      int ch = (vg >> 1) ^ ((hd ^ (hd >> 3)) & 15);
      *(uint2*)((char*)Vsm + hd * 256 + (ch << 4) + ((vg & 1) << 3)) = val;
    }
  };

  for (int pass = 0; pass < 2; ++pass) {
    const int qt = (pass == 0) ? (int)blockIdx.x : 15 - (int)blockIdx.x;
    const int q0 = qt * 128;
    const int nt = qt + 1;

    bf16x8 qa[4];
    {
      int row = q0 + w * 16 + lane16;
#pragma unroll
      for (int kk = 0; kk < 4; ++kk)
        qa[kk] = *(const bf16x8*)(Q + base + (size_t)row * HDD + kk * 32 + lgrp * 8);
    }

    f32x4 o[8] = {};
    float m_r[4], l_r[4];
#pragma unroll
    for (int r = 0; r < 4; ++r) { m_r[r] = NEG_INF; l_r[r] = 0.f; }

    for (int kt = 0; kt < nt; ++kt) {
      const int k0 = kt * 128;
      load_V(k0);           // V loads first (oldest in vmcnt queue)
      issue_K(k0);          // K direct-to-LDS, in flight during V repack
      write_V();            // waits only the 4 V loads; WAR safe (prev barrier)
      __syncthreads();      // drains vmcnt+lgkmcnt: K & V staged for all waves

      // ---- S = Q K^T
      f32x4 s[8] = {};
#pragma unroll
      for (int kk = 0; kk < 4; ++kk) {
#pragma unroll
        for (int nf = 0; nf < 8; ++nf) {
          int key = nf * 16 + lane16;
          int ch = (kk * 4 + lgrp) ^ ((key ^ (key >> 3)) & 15);
          bf16x8 kf = *(const bf16x8*)((char*)Ksm + key * 256 + (ch << 4));
          s[nf] = __builtin_amdgcn_mfma_f32_16x16x32_bf16(
              qa[kk], kf, s[nf], 0, 0, 0);
        }
      }

      // ---- scale + causal mask
      const int rowbase = q0 + w * 16 + lgrp * 4;
      const bool needmask = (k0 + 127 > q0 + w * 16);
#pragma unroll
      for (int nf = 0; nf < 8; ++nf) {
        int col = k0 + nf * 16 + lane16;
#pragma unroll
        for (int r = 0; r < 4; ++r) {
          float sv = s[nf][r] * ATT_SCALE;
          if (needmask && col > rowbase + r) sv = -3.0e38f;
          s[nf][r] = sv;
        }
      }

      // ---- online softmax
#pragma unroll
      for (int r = 0; r < 4; ++r) {
        float tm = fmaxf(fmaxf(fmaxf(s[0][r], s[1][r]), fmaxf(s[2][r], s[3][r])),
                         fmaxf(fmaxf(s[4][r], s[5][r]), fmaxf(s[6][r], s[7][r])));
        tm = fmaxf(tm, __shfl_xor(tm, 1));
        tm = fmaxf(tm, __shfl_xor(tm, 2));
        tm = fmaxf(tm, __shfl_xor(tm, 4));
        tm = fmaxf(tm, __shfl_xor(tm, 8));
        float mo = m_r[r];
        float mn = fmaxf(mo, tm);
        float alpha = exp2f((mo - mn) * L2E);
        m_r[r] = mn;
        float rs = 0.f;
#pragma unroll
        for (int nf = 0; nf < 8; ++nf) {
          float p = exp2f((s[nf][r] - mn) * L2E);
          s[nf][r] = p;
          rs += p;
        }
        rs += __shfl_xor(rs, 1);
        rs += __shfl_xor(rs, 2);
        rs += __shfl_xor(rs, 4);
        rs += __shfl_xor(rs, 8);
        l_r[r] = l_r[r] * alpha + rs;
#pragma unroll
        for (int nf = 0; nf < 8; ++nf) o[nf][r] *= alpha;
      }

      // ---- P -> LDS (per-wave region, same-wave readback; no barrier)
#pragma unroll
      for (int nf = 0; nf < 8; ++nf)
#pragma unroll
        for (int r = 0; r < 4; ++r) {
          int rl = lgrp * 4 + r;
          int ch = (2 * nf + (lane16 >> 3)) ^ ((rl ^ (rl >> 3)) & 15);
          int byte = rl * 256 + (ch << 4) + ((lane16 & 7) << 1);
          *(bf16*)((char*)&Psm[w][0] + byte) = (bf16)s[nf][r];
        }
      bf16x8 pa[4];
#pragma unroll
      for (int kk = 0; kk < 4; ++kk) {
        int ch = (kk * 4 + lgrp) ^ ((lane16 ^ (lane16 >> 3)) & 15);
        pa[kk] = *(const bf16x8*)((char*)&Psm[w][0] + lane16 * 256 + (ch << 4));
      }

      // ---- O += P V
#pragma unroll
      for (int nf = 0; nf < 8; ++nf) {
#pragma unroll
        for (int kk = 0; kk < 4; ++kk) {
          int hd = nf * 16 + lane16;
          int ch = (kk * 4 + lgrp) ^ ((hd ^ (hd >> 3)) & 15);
          bf16x8 vf = *(const bf16x8*)((char*)Vsm + hd * 256 + (ch << 4));
          o[nf] = __builtin_amdgcn_mfma_f32_16x16x32_bf16(
              pa[kk], vf, o[nf], 0, 0, 0);
        }
      }

      __syncthreads();      // all waves done reading Ksm/Vsm before next stage
    }

    // ---- finalize: O / l -> Y (b,t,D) bf16
#pragma unroll
    for (int r = 0; r < 4; ++r) {
      float inv = 1.0f / l_r[r];
      int row = q0 + w * 16 + lgrp * 4 + r;
#pragma unroll
      for (int nf = 0; nf < 8; ++nf) {
        int hd = nf * 16 + lane16;
        Y[(size_t)(b * TT + row) * DM + h * HDD + hd] = (bf16)(o[nf][r] * inv);
      }
    }
  }
}

// ---------------------------------------------------------------- launch
extern "C" void kernel_launch(void* const* d_in, const int* in_sizes, int n_in,
                              void* d_out, int out_size, void* d_ws, size_t ws_size,
                              hipStream_t stream) {
  const float* x = (const float*)d_in[0];
  const float* Wqkv = (const float*)d_in[2];
  const float* bqkv = (const float*)d_in[3];
  const float* Wproj = (const float*)d_in[4];
  const float* bproj = (const float*)d_in[5];
  float* out = (float*)d_out;

  char* ws = (char*)d_ws;
  bf16* xb = (bf16*)ws;                 ws += (size_t)MM * DM * 2;
  bf16* Wqkvt = (bf16*)ws;              ws += (size_t)NQKV * DM * 2;
  bf16* Wprojt = (bf16*)ws;             ws += (size_t)DM * DM * 2;
  bf16* kb = (bf16*)ws;                 ws += (size_t)MM * DM * 2;
  bf16* vb = (bf16*)ws;                 ws += (size_t)MM * DM * 2;
  float* cosT = (float*)ws;             ws += (size_t)TT * 64 * 4;
  float* sinT = (float*)ws;             ws += (size_t)TT * 64 * 4;
  bf16* qb = (bf16*)d_out;              // q lives in d_out (overwritten by proj)
  bf16* yb = xb;                        // xb dead after QKV GEMM

  rope_table_k<<<dim3(512), dim3(256), 0, stream>>>(cosT, sinT);
  convert_x_k<<<dim3(4096), dim3(256), 0, stream>>>(x, xb);
  transpose_w_k<<<dim3(96, 32), dim3(256), 0, stream>>>(Wqkv, Wqkvt, DM, NQKV);
  transpose_w_k<<<dim3(32, 32), dim3(256), 0, stream>>>(Wproj, Wprojt, DM, DM);

  gemm8_qkv_k<<<dim3(16, 32), dim3(512), 0, stream>>>(
      xb, Wqkvt, bqkv, qb, kb, vb, MM, NQKV, DM);

  rope_apply_k<<<dim3(4096), dim3(256), 0, stream>>>(qb, cosT, sinT);
  rope_apply_k<<<dim3(4096), dim3(256), 0, stream>>>(kb, cosT, sinT);

  attn_k<<<dim3(8, 32), dim3(512), 0, stream>>>(qb, kb, vb, yb);

  gemm4_proj_k<<<dim3(16, 16), dim3(512), 0, stream>>>(
      yb, Wprojt, bproj, out, MM, DM, DM);
}